// Round 5
// baseline (2380.632 us; speedup 1.0000x reference)
//
#include <hip/hip_runtime.h>

// TrajectoryTransformer fused bf16-MFMA implementation for MI355X (gfx950).
// B=256 T=100 IN=6 D=1024 H=8 HD=128 L=4 OUT=256.
// R7: embed de-transcendentalized (PE table).
// R8: main GEMMs -> gemm128: 128x256 tile, BK=32, 48KB LDS, per-wave 64x64
//     (acc 64 regs), __launch_bounds__(512,4) => <=128 unified regs =>
//     2 independent blocks/CU (16 waves). 2-phase/tile counted-vmcnt
//     pipeline (prefetch distance 2, vmcnt(3) steady state). Swizzle for
//     64B rows: chunk ^= (row>>1)&3 on both stage-source and read.
// R9/R10: resubmits — rounds 3+4 were broker-level failures ("container
//     failed twice", same class as R7's 40-min npz push on a sick pod).
//     Kernel audited: no divergent barriers (deadlock impossible), no OOB.
//     If this fails a third time: revert to proven R7 source to test the
//     channel, then reintroduce gemm128 piecewise.

#define B_    256
#define T_    100
#define D_    1024
#define H_    8
#define HD_   128
#define L_    4
#define BT_   25600          // B*T
#define DQ_   3072           // 3*D
#define OUT_  256
#define KFIN_ 102400         // T*D
#define KSPLIT_ 32
#define SCALE_ 0.08838834764831845f  // 1/sqrt(128)

typedef unsigned short ushort_t;
typedef __attribute__((ext_vector_type(8))) short bf16x8;   // 8 bf16 (4 VGPRs)
typedef __attribute__((ext_vector_type(4))) float f32x4;    // MFMA C/D

__device__ inline ushort_t f2bf(float f) {   // RNE fp32 -> bf16
  unsigned u = __float_as_uint(f);
  u += 0x7FFFu + ((u >> 16) & 1u);
  return (ushort_t)(u >> 16);
}
__device__ inline float bf2f(ushort_t u) {
  return __uint_as_float((unsigned)u << 16);
}

// async global->LDS, 16B per lane; LDS dest is wave-uniform base + lane*16
__device__ inline void gld16(const void* g, void* l) {
  __builtin_amdgcn_global_load_lds(
      (__attribute__((address_space(1))) unsigned int*)(size_t)g,
      (__attribute__((address_space(3))) unsigned int*)l, 16, 0, 0);
}

#define MFMA_(a, b, c) __builtin_amdgcn_mfma_f32_16x16x32_bf16(a, b, c, 0, 0, 0)

// ===========================================================================
// gemm128: C[m,n] = sum_k A[m,k]*Bw[n,k] + bias (+relu / +bf16-resid), bf16 out
// A:[M,1024] bf16 row-major, Bw:[N,1024] bf16 row-major. K fixed = 1024.
// Tile 128x256, BK=32, 32 K-tiles. 8 waves (2M x 4N), per-wave 64x64.
// LDS buf (24KB): A[128][32] @0 (64B rows), B[256][32] @8K. dbuf 48KB.
// 2 blocks/CU (reg-capped): independent barrier domains fill MFMA stalls.
// Swizzle: 16B chunk c' = c ^ ((row>>1)&3) — both-sides (stage src + read).
// Schedule/tile: {8 ds_read; lgkm0; 8 MFMA(j01); barrier; stage(t+2);
//                 8 MFMA(j23); vmcnt(3); barrier}.
// Hazards: tile t fully read before stage(t+2) issue (>=1 barrier);
//          vmcnt(3) at tile t ensures tile t+1 data landed before its reads.
// ===========================================================================
#define LBUF_ 24576

#define STG(t_) do { \
    const int lo__ = ((t_) & 1) * LBUF_; \
    gld16(gA  + (t_) * 32, lds + lo__ + dA); \
    gld16(gB0 + (t_) * 32, lds + lo__ + dB0); \
    gld16(gB1 + (t_) * 32, lds + lo__ + dB0 + 1024); \
  } while (0)

#define VM3_ asm volatile("s_waitcnt vmcnt(3)" ::: "memory")
#define VM0_ asm volatile("s_waitcnt vmcnt(0)" ::: "memory")

#define TIL(t_, STAGES_, VMW_) do { \
    const int lo_ = ((t_) & 1) * LBUF_; \
    _Pragma("unroll") for (int i_ = 0; i_ < 4; ++i_) \
      aF[i_] = *(const bf16x8*)(lds + lo_ + rbA + i_ * 1024 + cR); \
    _Pragma("unroll") for (int j_ = 0; j_ < 4; ++j_) \
      bF[j_] = *(const bf16x8*)(lds + lo_ + rbB + j_ * 1024 + cR); \
    asm volatile("s_waitcnt lgkmcnt(0)" ::: "memory"); \
    __builtin_amdgcn_sched_barrier(0); \
    __builtin_amdgcn_s_setprio(1); \
    _Pragma("unroll") for (int i_ = 0; i_ < 4; ++i_) { \
      acc[i_][0] = MFMA_(aF[i_], bF[0], acc[i_][0]); \
      acc[i_][1] = MFMA_(aF[i_], bF[1], acc[i_][1]); } \
    __builtin_amdgcn_s_setprio(0); \
    __builtin_amdgcn_s_barrier(); \
    __builtin_amdgcn_sched_barrier(0); \
    STAGES_; \
    __builtin_amdgcn_s_setprio(1); \
    _Pragma("unroll") for (int i_ = 0; i_ < 4; ++i_) { \
      acc[i_][2] = MFMA_(aF[i_], bF[2], acc[i_][2]); \
      acc[i_][3] = MFMA_(aF[i_], bF[3], acc[i_][3]); } \
    __builtin_amdgcn_s_setprio(0); \
    VMW_; \
    __builtin_amdgcn_s_barrier(); \
    __builtin_amdgcn_sched_barrier(0); \
  } while (0)

template<int RELU, int RESID>
__global__ __launch_bounds__(512, 4)
void gemm128(const ushort_t* __restrict__ A, const ushort_t* __restrict__ Bw,
             const float* __restrict__ bias,
             ushort_t* __restrict__ outb, const ushort_t* __restrict__ resid,
             int N)
{
  __shared__ __align__(16) char lds[49152];
  const int tid = threadIdx.x;
  const int lane = tid & 63, w = tid >> 6;
  const int fr = lane & 15, q = lane >> 4;
  const int wm = w >> 2, wn = w & 3;          // 2M x 4N wave grid

  // bijective XCD-aware block swizzle (T1, m204 form); nwg % 8 == 0 here
  const int nwg = gridDim.x;
  const int nbx = N >> 8;
  const int qd = nwg >> 3, r8 = nwg & 7;
  const int xcd = blockIdx.x & 7, idx = blockIdx.x >> 3;
  const int wg = (xcd < r8 ? xcd * (qd + 1) : r8 * (qd + 1) + (xcd - r8) * qd) + idx;
  const int m0 = (wg / nbx) * 128, n0 = (wg % nbx) * 256;

  // staging: per tile each wave issues A(1KB: rows w*16..+15) + B(2KB: rows
  // w*32..+31). Source chunk pre-swizzled: c' = (l&3) ^ ((l>>3)&3)
  // == (l&3) ^ ((localrow>>1)&3) since localrow = l>>2.
  const int xc = (lane & 3) ^ ((lane >> 3) & 3);
  const ushort_t* gA  = A  + (size_t)(m0 + w * 16 + (lane >> 2)) * 1024 + xc * 8;
  const ushort_t* gB0 = Bw + (size_t)(n0 + w * 32 + (lane >> 2)) * 1024 + xc * 8;
  const ushort_t* gB1 = gB0 + 16 * 1024;
  const int dA  = w * 1024;
  const int dB0 = 8192 + w * 2048;

  // read addressing: frag rows = 16k + fr -> swizzle key (fr>>1)&3
  const int cR  = fr * 64 + ((q ^ ((fr >> 1) & 3)) << 4);
  const int rbA = wm * 4096;          // + i*1024
  const int rbB = 8192 + wn * 4096;   // + j*1024

  f32x4 acc[4][4];
  #pragma unroll
  for (int i = 0; i < 4; ++i)
    #pragma unroll
    for (int j = 0; j < 4; ++j) acc[i][j] = 0.f;
  bf16x8 aF[4], bF[4];

  // prologue: stage tiles 0,1; wait tile0 (3 of 6 outstanding) landed
  STG(0); STG(1);
  VM3_;
  __builtin_amdgcn_s_barrier();
  __builtin_amdgcn_sched_barrier(0);

  #pragma unroll
  for (int t = 0; t < 30; ++t) TIL(t, STG(t + 2), VM3_);
  TIL(30, (void)0, VM0_);             // drain: tile31 data fully landed
  TIL(31, (void)0, (void)0);
  __syncthreads();                    // LDS reuse for epilogue staging

  // -------- epilogue: bias/relu/resid + coalesced bf16 store via LDS --------
  const int erow = lane >> 2;         // 0..15
  const int ecc  = lane & 3;          // 16B chunk 0..3
  char* wb = lds + w * 4096;          // private 4KB per wave
  float bvv[2][2];
  #pragma unroll
  for (int jh = 0; jh < 2; ++jh)
    #pragma unroll
    for (int jn = 0; jn < 2; ++jn)
      bvv[jh][jn] = bias ? bias[n0 + wn * 64 + jh * 32 + jn * 16 + fr] : 0.f;

  #pragma unroll
  for (int jh = 0; jh < 2; ++jh) {    // column halves (32 cols each)
    #pragma unroll
    for (int i = 0; i < 4; ++i)
      #pragma unroll
      for (int jn = 0; jn < 2; ++jn)
        #pragma unroll
        for (int rr = 0; rr < 4; ++rr) {
          const int row = i * 16 + q * 4 + rr;      // 0..63
          float v = acc[i][jh * 2 + jn][rr] + bvv[jh][jn];
          if (RELU) v = fmaxf(v, 0.f);
          const int cp = (jn * 2 + (fr >> 3)) ^ ((row >> 2) & 3);
          *(ushort_t*)(wb + row * 64 + cp * 16 + (fr & 7) * 2) = f2bf(v);
        }
    #pragma unroll
    for (int rd = 0; rd < 4; ++rd) {
      const int row = rd * 16 + erow;
      const int sc = ecc ^ ((row >> 2) & 3);
      bf16x8 seg = *(const bf16x8*)(wb + row * 64 + sc * 16);
      const size_t gaddr = (size_t)(m0 + wm * 64 + row) * N
                         + (n0 + wn * 64 + jh * 32 + ecc * 8);
      if (RESID) {
        const bf16x8 rv = *(const bf16x8*)&resid[gaddr];
        #pragma unroll
        for (int e = 0; e < 8; ++e)
          seg[e] = (short)f2bf(bf2f((ushort_t)seg[e]) + bf2f((ushort_t)rv[e]));
      }
      *(bf16x8*)&outb[gaddr] = seg;
    }
  }
}

// ---------------------------------------------------------------------------
// Legacy 128x128 GEMM — retained ONLY for the final split-K fp32-partial GEMM.
// ---------------------------------------------------------------------------
template<int RELU, int RESID, int OBF, int OF32>
__global__ __launch_bounds__(256)
void gemm_nt(const ushort_t* __restrict__ A, const ushort_t* __restrict__ Bw,
             const float* __restrict__ bias,
             ushort_t* outb, float* outf, const ushort_t* __restrict__ resid,
             int M, int N, int K, int ksteps)
{
  __shared__ ushort_t lds[16384];      // A: [0,8192), B: [8192,16384)  (32 KB)
  ushort_t* lsA = lds;
  ushort_t* lsB = lds + 8192;
  const int tid = threadIdx.x, lane = tid & 63, wave = tid >> 6;
  const int fr = lane & 15, q = lane >> 4;
  const int m0 = blockIdx.y * 128, n0 = blockIdx.x * 128;
  const int wm = (wave >> 1) * 64, wn = (wave & 1) * 64;
  const int kbase = blockIdx.z * ksteps * 64;

  const ushort_t* Ab = A + (size_t)m0 * K + kbase;
  const ushort_t* Bb = Bw + (size_t)n0 * K + kbase;

  const int kg = (lane & 7) ^ (lane >> 3);
  const ushort_t* gaA = Ab + (size_t)(lane >> 3) * K + kg * 8;
  const ushort_t* gaB = Bb + (size_t)(lane >> 3) * K + kg * 8;

  f32x4 acc[4][4];
  #pragma unroll
  for (int i = 0; i < 4; i++)
    #pragma unroll
    for (int j = 0; j < 4; j++) acc[i][j] = 0.f;

  int rowA[4], rowB[4];
  #pragma unroll
  for (int t = 0; t < 4; t++) {
    rowA[t] = (wm + t * 16 + fr) * 64;
    rowB[t] = (wn + t * 16 + fr) * 64;
  }
  const int sl0 = ((0 * 4 + q) ^ (fr & 7)) * 8;
  const int sl1 = ((1 * 4 + q) ^ (fr & 7)) * 8;

  for (int ks = 0; ks < ksteps; ks++) {
    __syncthreads();
    #pragma unroll
    for (int u = 0; u < 4; u++) {
      const int i = wave * 4 + u;
      gld16(gaA + ks * 64 + (size_t)i * 8 * K, lsA + i * 512);
      gld16(gaB + ks * 64 + (size_t)i * 8 * K, lsB + i * 512);
    }
    __syncthreads();
    #pragma unroll
    for (int s = 0; s < 2; s++) {
      const int sl = s ? sl1 : sl0;
      bf16x8 af[4], bfv[4];
      #pragma unroll
      for (int t = 0; t < 4; t++) {
        af[t]  = *(const bf16x8*)(lsA + rowA[t] + sl);
        bfv[t] = *(const bf16x8*)(lsB + rowB[t] + sl);
      }
      #pragma unroll
      for (int i = 0; i < 4; i++)
        #pragma unroll
        for (int j = 0; j < 4; j++)
          acc[i][j] = __builtin_amdgcn_mfma_f32_16x16x32_bf16(af[i], bfv[j], acc[i][j], 0, 0, 0);
    }
  }

  if (OF32) {  // fp32 split-K partial (final GEMM only; small output)
    float* po = outf + (size_t)blockIdx.z * M * N;
    #pragma unroll
    for (int i = 0; i < 4; i++) {
      const int rb = m0 + wm + i * 16 + q * 4;
      #pragma unroll
      for (int j = 0; j < 4; j++) {
        const int col = n0 + wn + j * 16 + fr;
        #pragma unroll
        for (int rr = 0; rr < 4; rr++)
          po[(size_t)(rb + rr) * N + col] = acc[i][j][rr];
      }
    }
  }
}

// ---------------------------------------------------------------------------
// Fused attention R5: one block per (head, batch). qkv:[BT,3072] bf16.
// ---------------------------------------------------------------------------
#define KST 136   // Kls row stride (bf16): 272B rows, 2-way banks (free)
#define VST 120   // Vt row stride (bf16)
#define PST 120   // Pls row stride (bf16)

__global__ __launch_bounds__(256)
void attn_kernel(const ushort_t* __restrict__ qkv, ushort_t* __restrict__ ctx)
{
  __shared__ ushort_t Kls[112 * KST];  // 30464 B
  __shared__ ushort_t Vt[128 * VST];   // 30720 B
  __shared__ ushort_t Pls[64 * PST];   // 15360 B  (total 76544 B -> 2 blk/CU)
  const int tid = threadIdx.x, lane = tid & 63, wave = tid >> 6;
  const int fr = lane & 15, q = lane >> 4;
  const int hh = blockIdx.x, bb = blockIdx.y;
  const size_t base = (size_t)bb * T_ * DQ_;
  const ushort_t* Qb = qkv + base + hh * HD_;
  const ushort_t* Kb = qkv + base + D_ + hh * HD_;
  const ushort_t* Vb = qkv + base + 2 * D_ + hh * HD_;

  for (int e = tid; e < 1600; e += 256) {
    const int j = e >> 4, kc = e & 15;
    *(bf16x8*)&Kls[j * KST + kc * 8] = *(const bf16x8*)(Kb + (size_t)j * DQ_ + kc * 8);
  }
  for (int e = tid; e < 12 * KST; e += 256) Kls[100 * KST + e] = 0;
  for (int e = tid; e < 1600; e += 256) {
    const int j = e >> 4, dc = e & 15;
    const bf16x8 v = *(const bf16x8*)(Vb + (size_t)j * DQ_ + dc * 8);
    #pragma unroll
    for (int u = 0; u < 8; u++) Vt[(dc * 8 + u) * VST + j] = (ushort_t)v[u];
  }
  for (int e = tid; e < 128 * 12; e += 256) {
    const int d = e / 12, j = e - d * 12;
    Vt[d * VST + 100 + j] = 0;
  }
  __syncthreads();

  for (int c = 0; c < 2; c++) {
    if (c) __syncthreads();
    const int it  = c * 4 + wave;
    const bool wlive = (it < 7);
    const int itc = wlive ? it : 6;
    const int qrow = min(itc * 16 + fr, T_ - 1);
    bf16x8 aq[4];
    #pragma unroll
    for (int ks = 0; ks < 4; ks++)
      aq[ks] = *(const bf16x8*)(Qb + (size_t)qrow * DQ_ + ks * 32 + q * 8);
    f32x4 sacc[7];
    #pragma unroll
    for (int jt = 0; jt < 7; jt++) sacc[jt] = 0.f;
    #pragma unroll
    for (int ks = 0; ks < 4; ks++) {
      const int kk = ks * 32 + q * 8;
      #pragma unroll
      for (int jt = 0; jt < 7; jt++) {
        const bf16x8 kb = *(const bf16x8*)&Kls[(jt * 16 + fr) * KST + kk];
        sacc[jt] = __builtin_amdgcn_mfma_f32_16x16x32_bf16(aq[ks], kb, sacc[jt], 0, 0, 0);
      }
    }
    ushort_t pbf[7][4];
    #pragma unroll
    for (int rr = 0; rr < 4; rr++) {
      float sv[7];
      float mx = -1e30f;
      #pragma unroll
      for (int jt = 0; jt < 7; jt++) {
        float s = sacc[jt][rr] * SCALE_;
        if (jt == 6 && fr >= 4) s = -1e30f;
        sv[jt] = s;
        mx = fmaxf(mx, s);
      }
      mx = fmaxf(mx, __shfl_xor(mx, 1));
      mx = fmaxf(mx, __shfl_xor(mx, 2));
      mx = fmaxf(mx, __shfl_xor(mx, 4));
      mx = fmaxf(mx, __shfl_xor(mx, 8));
      float sum = 0.f;
      #pragma unroll
      for (int jt = 0; jt < 7; jt++) { sv[jt] = __expf(sv[jt] - mx); sum += sv[jt]; }
      sum += __shfl_xor(sum, 1);
      sum += __shfl_xor(sum, 2);
      sum += __shfl_xor(sum, 4);
      sum += __shfl_xor(sum, 8);
      const float inv = 1.f / sum;
      #pragma unroll
      for (int jt = 0; jt < 7; jt++) pbf[jt][rr] = f2bf(sv[jt] * inv);
    }
    if (wlive) {
      #pragma unroll
      for (int jt = 0; jt < 7; jt++)
        #pragma unroll
        for (int rr = 0; rr < 4; rr++)
          Pls[(wave * 16 + q * 4 + rr) * PST + jt * 16 + fr] = pbf[jt][rr];
    }
    __syncthreads();
    const int mtc = (c == 0) ? 4 : 3;
    f32x4 cacc[4][2];
    #pragma unroll
    for (int i = 0; i < 4; i++) { cacc[i][0] = 0.f; cacc[i][1] = 0.f; }
    #pragma unroll
    for (int ks = 0; ks < 4; ks++) {
      const int kk = ks * 32 + q * 8;
      const bool live = (ks < 3) || (q < 2);
      bf16x8 v0 = 0, v1 = 0;
      if (live) {
        v0 = *(const bf16x8*)&Vt[((wave * 2 + 0) * 16 + fr) * VST + kk];
        v1 = *(const bf16x8*)&Vt[((wave * 2 + 1) * 16 + fr) * VST + kk];
      }
      for (int mt = 0; mt < mtc; mt++) {
        bf16x8 a = 0;
        if (live) a = *(const bf16x8*)&Pls[(mt * 16 + fr) * PST + kk];
        cacc[mt][0] = __builtin_amdgcn_mfma_f32_16x16x32_bf16(a, v0, cacc[mt][0], 0, 0, 0);
        cacc[mt][1] = __builtin_amdgcn_mfma_f32_16x16x32_bf16(a, v1, cacc[mt][1], 0, 0, 0);
      }
    }
    for (int mt = 0; mt < mtc; mt++) {
      #pragma unroll
      for (int nn = 0; nn < 2; nn++) {
        const int col = hh * HD_ + (wave * 2 + nn) * 16 + fr;
        #pragma unroll
        for (int rr = 0; rr < 4; rr++) {
          const int r = c * 64 + mt * 16 + q * 4 + rr;
          if (r < T_)
            ctx[(size_t)(bb * T_ + r) * D_ + col] = f2bf(cacc[mt][nn][rr]);
        }
      }
    }
  }
}

// ---------------------------------------------------------------------------
// LayerNorm: bf16 in -> bf16 out (fp32 stats). One block per row.
// ---------------------------------------------------------------------------
__global__ __launch_bounds__(256)
void ln_kernel(const ushort_t* __restrict__ in, ushort_t* __restrict__ outb,
               const float* __restrict__ g, const float* __restrict__ bta)
{
  const int row = blockIdx.x, tid = threadIdx.x;
  const int c4 = tid * 4;
  const ushort4 uv = *(const ushort4*)(in + (size_t)row * D_ + c4);
  const float v0 = bf2f(uv.x), v1 = bf2f(uv.y), v2 = bf2f(uv.z), v3 = bf2f(uv.w);
  float s  = v0 + v1 + v2 + v3;
  float ss = v0*v0 + v1*v1 + v2*v2 + v3*v3;
  #pragma unroll
  for (int o = 1; o < 64; o <<= 1) {
    s  += __shfl_xor(s, o);
    ss += __shfl_xor(ss, o);
  }
  __shared__ float red[8];
  const int lane = tid & 63, wave = tid >> 6;
  if (lane == 0) { red[wave] = s; red[4 + wave] = ss; }
  __syncthreads();
  s  = red[0] + red[1] + red[2] + red[3];
  ss = red[4] + red[5] + red[6] + red[7];
  const float mean = s * (1.f / D_);
  const float var  = ss * (1.f / D_) - mean * mean;
  const float rstd = rsqrtf(var + 1e-5f);
  const float4 gv = *(const float4*)(g + c4);
  const float4 bv = *(const float4*)(bta + c4);
  ushort4 ob = { f2bf((v0 - mean) * rstd * gv.x + bv.x),
                 f2bf((v1 - mean) * rstd * gv.y + bv.y),
                 f2bf((v2 - mean) * rstd * gv.z + bv.z),
                 f2bf((v3 - mean) * rstd * gv.w + bv.w) };
  *(ushort4*)(outb + (size_t)row * D_ + c4) = ob;
}

// ---------------------------------------------------------------------------
// PE table: pe[t][d] for t<T, d<D. 100 blocks x 256 thr; 512 sincos pairs/row.
// ---------------------------------------------------------------------------
__global__ __launch_bounds__(256)
void pe_init(float* __restrict__ pe)
{
  const int t = blockIdx.x;
  #pragma unroll
  for (int j = 0; j < 2; ++j) {
    const int k = threadIdx.x + j * 256;        // 0..511
    const float ang = (float)t * expf((float)k * -0.017988946039015984f);
    float s, c;
    sincosf(ang, &s, &c);
    pe[t * D_ + 2 * k]     = s;
    pe[t * D_ + 2 * k + 1] = c;
  }
}

// ---------------------------------------------------------------------------
// Embedding: h = x@Wi + bi + pe[t,:] -> bf16. One block per token row.
// ---------------------------------------------------------------------------
__global__ __launch_bounds__(256)
void embed_kernel(const float* __restrict__ x, const float* __restrict__ Wi,
                  const float* __restrict__ bi, const float* __restrict__ pe,
                  ushort_t* __restrict__ hbf)
{
  const int row = blockIdx.x;
  const int t = row % T_;
  const int c = threadIdx.x * 4;
  float xv[6];
  #pragma unroll
  for (int i = 0; i < 6; i++) xv[i] = x[row * 6 + i];
  const float4 pv = *(const float4*)(pe + t * D_ + c);
  const float4 bv = *(const float4*)(bi + c);
  float a0 = bv.x + pv.x, a1 = bv.y + pv.y, a2 = bv.z + pv.z, a3 = bv.w + pv.w;
  #pragma unroll
  for (int i = 0; i < 6; i++) {
    const float4 wv = *(const float4*)(Wi + i * D_ + c);
    a0 += xv[i] * wv.x; a1 += xv[i] * wv.y;
    a2 += xv[i] * wv.z; a3 += xv[i] * wv.w;
  }
  ushort4 ob = { f2bf(a0), f2bf(a1), f2bf(a2), f2bf(a3) };
  *(ushort4*)(hbf + (size_t)row * D_ + c) = ob;
}

// All weight tensors -> bf16 in one launch.
#define NQW (L_*DQ_*D_)   // 12582912
#define NDW (L_*D_*D_)    //  4194304
__global__ void cvt_all(const float* __restrict__ qw, const float* __restrict__ ow,
                        const float* __restrict__ f1, const float* __restrict__ f2,
                        ushort_t* wq, ushort_t* wo, ushort_t* w1, ushort_t* w2)
{
  const size_t i = ((size_t)blockIdx.x * 256 + threadIdx.x) * 4;
  const float* s; ushort_t* d; size_t off;
  if (i < NQW)                { s = qw; d = wq; off = i; }
  else if (i < NQW + NDW)     { s = ow; d = wo; off = i - NQW; }
  else if (i < NQW + 2*NDW)   { s = f1; d = w1; off = i - NQW - NDW; }
  else                        { s = f2; d = w2; off = i - NQW - 2*NDW; }
  const float4 v = *(const float4*)(s + off);
  ushort4 o = { f2bf(v.x), f2bf(v.y), f2bf(v.z), f2bf(v.w) };
  *(ushort4*)(d + off) = o;
}

// Wo [KFIN,256] fp32 -> Wot [256,KFIN] bf16
__global__ __launch_bounds__(256)
void transpose_wo(const float* __restrict__ src, ushort_t* __restrict__ dst)
{
  __shared__ float tile[64][65];
  const int k0 = blockIdx.x * 64, n0 = blockIdx.y * 64;
  const int tc = threadIdx.x & 63, tr = threadIdx.x >> 6;
  #pragma unroll
  for (int i = 0; i < 16; i++) {
    const int r = i * 4 + tr;
    tile[r][tc] = src[(size_t)(k0 + r) * OUT_ + n0 + tc];
  }
  __syncthreads();
  #pragma unroll
  for (int i = 0; i < 16; i++) {
    const int n = i * 4 + tr;
    dst[(size_t)(n0 + n) * KFIN_ + k0 + tc] = f2bf(tile[tc][n]);
  }
}

__global__ void reduce_final(const float* __restrict__ part,
                             const float* __restrict__ bo, float* __restrict__ out)
{
  const int i = blockIdx.x * 256 + threadIdx.x;   // 65536 outputs
  float s = bo[i & (OUT_ - 1)];
  for (int z = 0; z < KSPLIT_; z++) s += part[(size_t)z * OUT_ * OUT_ + i];
  out[i] = s;
}

// ---------------------------------------------------------------------------
extern "C" void kernel_launch(void* const* d_in, const int* in_sizes, int n_in,
                              void* d_out, int out_size, void* d_ws, size_t ws_size,
                              hipStream_t stream)
{
  (void)in_sizes; (void)n_in; (void)out_size; (void)ws_size;
  const float* x     = (const float*)d_in[0];
  const float* Wi    = (const float*)d_in[1];
  const float* bi    = (const float*)d_in[2];
  const float* qkv_w = (const float*)d_in[3];
  const float* qkv_b = (const float*)d_in[4];
  const float* out_w = (const float*)d_in[5];
  const float* out_b = (const float*)d_in[6];
  const float* ff1_w = (const float*)d_in[7];
  const float* ff1_b = (const float*)d_in[8];
  const float* ff2_w = (const float*)d_in[9];
  const float* ff2_b = (const float*)d_in[10];
  const float* ln1_g = (const float*)d_in[11];
  const float* ln1_b = (const float*)d_in[12];
  const float* ln2_g = (const float*)d_in[13];
  const float* ln2_b = (const float*)d_in[14];
  const float* Wo    = (const float*)d_in[15];
  const float* bo    = (const float*)d_in[16];
  float* out = (float*)d_out;

  // workspace layout — ~313 MiB peak
  char* p = (char*)d_ws;
  ushort_t* hbf  = (ushort_t*)p; p += (size_t)BT_ * D_ * 2;     //  52.4 MB
  ushort_t* qkvb = (ushort_t*)p; p += (size_t)BT_ * DQ_ * 2;    // 157.3 MB
  ushort_t* ctxb = (ushort_t*)p; p += (size_t)BT_ * D_ * 2;     //  52.4 MB
  ushort_t* wq   = (ushort_t*)p; p += (size_t)NQW * 2;          //  25.2 MB
  ushort_t* wo   = (ushort_t*)p; p += (size_t)NDW * 2;          //   8.4 MB
  ushort_t* w1   = (ushort_t*)p; p += (size_t)NDW * 2;          //   8.4 MB
  ushort_t* w2   = (ushort_t*)p; p += (size_t)NDW * 2;          //   8.4 MB
  float*    pe   = (float*)p;    p += (size_t)T_ * D_ * 4;      //   0.4 MB
  ushort_t* ffact = qkvb;                         // qkv dead after attention
  ushort_t* sum   = qkvb + (size_t)BT_ * D_;      // pre-LN sum (slot 1)
  ushort_t* wot   = ctxb;                         // ctx dead after last out-proj
  float*    part  = (float*)qkvb;                 // final split-K partials

  cvt_all<<<dim3((NQW + 3*NDW) / 1024), 256, 0, stream>>>(
      qkv_w, out_w, ff1_w, ff2_w, wq, wo, w1, w2);
  pe_init<<<dim3(T_), 256, 0, stream>>>(pe);
  embed_kernel<<<dim3(BT_), 256, 0, stream>>>(x, Wi, bi, pe, hbf);

  for (int i = 0; i < L_; i++) {
    // qkv = h @ qkv_w^T + b  -> bf16   (M=25600, N=3072; 2400 wgs @ 2 blk/CU)
    gemm128<0,0><<<dim3((BT_/128)*(DQ_/256)), 512, 0, stream>>>(
        hbf, wq + (size_t)i * DQ_ * D_, qkv_b + i * DQ_, qkvb, nullptr, DQ_);
    attn_kernel<<<dim3(H_, B_), 256, 0, stream>>>(qkvb, ctxb);
    // sum = ctx @ out_w^T + b + h   (bf16)  (800 wgs)
    gemm128<0,1><<<dim3((BT_/128)*(D_/256)), 512, 0, stream>>>(
        ctxb, wo + (size_t)i * D_ * D_, out_b + i * D_, sum, hbf, D_);
    ln_kernel<<<dim3(BT_), 256, 0, stream>>>(sum, hbf, ln1_g + i * D_, ln1_b + i * D_);
    // ff = relu(h @ ff1^T + b) -> bf16
    gemm128<1,0><<<dim3((BT_/128)*(D_/256)), 512, 0, stream>>>(
        hbf, w1 + (size_t)i * D_ * D_, ff1_b + i * D_, ffact, nullptr, D_);
    // sum = ff @ ff2^T + b + h   (bf16)
    gemm128<0,1><<<dim3((BT_/128)*(D_/256)), 512, 0, stream>>>(
        ffact, w2 + (size_t)i * D_ * D_, ff2_b + i * D_, sum, hbf, D_);
    ln_kernel<<<dim3(BT_), 256, 0, stream>>>(sum, hbf, ln2_g + i * D_, ln2_b + i * D_);
  }

  // final: out = h.reshape(256,102400) @ Wo + bo   (split-K partials + reduce)
  transpose_wo<<<dim3(KFIN_/64, OUT_/64), 256, 0, stream>>>(Wo, wot);
  gemm_nt<0,0,0,1><<<dim3(OUT_/128, OUT_/128, KSPLIT_), 256, 0, stream>>>(
      hbf, wot, nullptr, nullptr, part, nullptr,
      OUT_, OUT_, KFIN_, KFIN_ / (KSPLIT_ * 64));
  reduce_final<<<dim3(OUT_ * OUT_ / 256), 256, 0, stream>>>(part, bo, out);
}

// Round 6
// 2200.272 us; speedup vs baseline: 1.0820x; 1.0820x over previous
//
#include <hip/hip_runtime.h>

// TrajectoryTransformer fused bf16-MFMA implementation for MI355X (gfx950).
// B=256 T=100 IN=6 D=1024 H=8 HD=128 L=4 OUT=256.
// R7: embed de-transcendentalized (PE table).
// R8/R10: gemm128 (128x256, 2 blk/CU) — measured: QKV 172.9us (worse than
//     gemm256's 163.6; LDS-read-bound at 64x64/wave), D-GEMMs ~29us better
//     net (totals R7 2372 vs R10 2380 with QKV +37).
// R11: HYBRID — gemm256 (256x256 8-phase, measured best) for QKV;
//     gemm128 for the 12 D-GEMMs. attn: forced unroll on c/mt loops so
//     cacc[] indexing is compile-time (rule #20 scratch guard).

#define B_    256
#define T_    100
#define D_    1024
#define H_    8
#define HD_   128
#define L_    4
#define BT_   25600          // B*T
#define DQ_   3072           // 3*D
#define OUT_  256
#define KFIN_ 102400         // T*D
#define KSPLIT_ 32
#define SCALE_ 0.08838834764831845f  // 1/sqrt(128)

typedef unsigned short ushort_t;
typedef __attribute__((ext_vector_type(8))) short bf16x8;   // 8 bf16 (4 VGPRs)
typedef __attribute__((ext_vector_type(4))) float f32x4;    // MFMA C/D

__device__ inline ushort_t f2bf(float f) {   // RNE fp32 -> bf16
  unsigned u = __float_as_uint(f);
  u += 0x7FFFu + ((u >> 16) & 1u);
  return (ushort_t)(u >> 16);
}
__device__ inline float bf2f(ushort_t u) {
  return __uint_as_float((unsigned)u << 16);
}

// async global->LDS, 16B per lane; LDS dest is wave-uniform base + lane*16
__device__ inline void gld16(const void* g, void* l) {
  __builtin_amdgcn_global_load_lds(
      (__attribute__((address_space(1))) unsigned int*)(size_t)g,
      (__attribute__((address_space(3))) unsigned int*)l, 16, 0, 0);
}

#define MFMA_(a, b, c) __builtin_amdgcn_mfma_f32_16x16x32_bf16(a, b, c, 0, 0, 0)

#define VM6_ asm volatile("s_waitcnt vmcnt(6)" ::: "memory")
#define VM3_ asm volatile("s_waitcnt vmcnt(3)" ::: "memory")
#define VM0_ asm volatile("s_waitcnt vmcnt(0)" ::: "memory")

// ===========================================================================
// gemm256: 256x256 tile, BK=64, 16 K-tiles, 8 waves (2M x 4N), per-wave
// 128x64. 8-phase counted-vmcnt schedule, 128KB LDS dbuf, 1 blk/CU.
// Measured (R6): QKV 163.6us, MfmaUtil 42%. Best for large-grid GEMMs.
// ===========================================================================
#define GBUF_ 65536
#define GBOF_ 32768

#define STAGE256(hs_) do { \
    const int hs__ = (hs_); \
    if (hs__ < 64) { \
      const int tt__ = hs__ >> 2, id__ = hs__ & 3; \
      const int half__ = id__ >> 1; \
      const int bo__ = (tt__ & 1) * GBUF_ + half__ * 16384 + wsl \
                     + ((id__ & 1) ? GBOF_ : 0); \
      const ushort_t* s__ = ((id__ & 1) ? gB : gA) \
                     + (size_t)(half__ * 128) * 1024 + tt__ * 64; \
      gld16(s__, lds + bo__); \
      gld16(s__ + 8 * 1024, lds + bo__ + 1024); \
    } \
  } while (0)

#define LDA256(Mi) do { \
    const char* ba__ = lds + ldsoff + (Mi) * 16384 + rbA; \
    _Pragma("unroll") for (int i_ = 0; i_ < 4; ++i_) { \
      aF[i_][0] = *(const bf16x8*)(ba__ + i_ * 2048 + c0); \
      aF[i_][1] = *(const bf16x8*)(ba__ + i_ * 2048 + c1); \
    } \
  } while (0)

#define LDB256(Ni, BF) do { \
    const char* bb__ = lds + ldsoff + (Ni) * 16384 + rbB; \
    _Pragma("unroll") for (int j_ = 0; j_ < 2; ++j_) { \
      BF[j_][0] = *(const bf16x8*)(bb__ + j_ * 2048 + c0); \
      BF[j_][1] = *(const bf16x8*)(bb__ + j_ * 2048 + c1); \
    } \
  } while (0)

#define MM256(Mi, Ni, BF) do { \
    _Pragma("unroll") for (int i_ = 0; i_ < 4; ++i_) \
      _Pragma("unroll") for (int j_ = 0; j_ < 2; ++j_) { \
        acc[Mi][Ni][i_][j_] = MFMA_(aF[i_][0], BF[j_][0], acc[Mi][Ni][i_][j_]); \
        acc[Mi][Ni][i_][j_] = MFMA_(aF[i_][1], BF[j_][1], acc[Mi][Ni][i_][j_]); \
      } \
  } while (0)

#define PH256(t, p, LOADS, Mi, Ni, BF, VM) do { \
    LOADS; \
    STAGE256(7 + 4 * (t) + (p)); \
    __builtin_amdgcn_s_barrier(); \
    asm volatile("s_waitcnt lgkmcnt(0)" ::: "memory"); \
    __builtin_amdgcn_sched_barrier(0); \
    __builtin_amdgcn_s_setprio(1); \
    MM256(Mi, Ni, BF); \
    __builtin_amdgcn_s_setprio(0); \
    VM; \
    __builtin_amdgcn_s_barrier(); \
  } while (0)

#define TILE256(t, VM) do { \
    const int ldsoff = ((t) & 1) * GBUF_; \
    PH256(t, 0, { LDA256(0); LDB256(0, bF0); }, 0, 0, bF0, (void)0); \
    PH256(t, 1, { LDB256(1, bF1); },            0, 1, bF1, (void)0); \
    PH256(t, 2, { LDA256(1); },                 1, 1, bF1, (void)0); \
    PH256(t, 3, { },                            1, 0, bF0, VM); \
  } while (0)

template<int RELU, int RESID>
__global__ __launch_bounds__(512, 1)
void gemm256(const ushort_t* __restrict__ A, const ushort_t* __restrict__ Bw,
             const float* __restrict__ bias,
             ushort_t* __restrict__ outb, const ushort_t* __restrict__ resid,
             int N)
{
  __shared__ char lds[131072];
  const int tid = threadIdx.x;
  const int lane = tid & 63, w = tid >> 6;
  const int fr = lane & 15, q = lane >> 4;
  const int wm = w >> 2, wn = w & 3;          // 2 x 4 wave grid

  // bijective XCD-aware block swizzle (T1, m204 form)
  const int nwg = gridDim.x;
  const int nbx = N >> 8;
  const int qd = nwg >> 3, r8 = nwg & 7;
  const int xcd = blockIdx.x & 7, idx = blockIdx.x >> 3;
  const int wg = (xcd < r8 ? xcd * (qd + 1) : r8 * (qd + 1) + (xcd - r8) * qd) + idx;
  const int m0 = (wg / nbx) * 256, n0 = (wg % nbx) * 256;

  // staging: wave w covers 16 rows (w*16 + j*8 + lane/8) of each 128-row half
  const int lr8 = lane >> 3;
  const int xch = (lane & 7) ^ lr8;           // pre-swizzled source chunk
  const ushort_t* gA = A  + (size_t)(m0 + w * 16 + lr8) * 1024 + xch * 8;
  const ushort_t* gB = Bw + (size_t)(n0 + w * 16 + lr8) * 1024 + xch * 8;
  const int wsl = w * 2048;                   // LDS dest slice (2 x 1KB issues)

  // read addressing (swizzled chunks; row&7 == fr&7 for all fragment rows)
  const int c0 = (q ^ (fr & 7)) * 16;         // kk=0
  const int c1 = ((4 + q) ^ (fr & 7)) * 16;   // kk=1
  const int rbA = (wm * 64 + fr) * 128;
  const int rbB = GBOF_ + (wn * 32 + fr) * 128;

  f32x4 acc[2][2][4][2];
  #pragma unroll
  for (int a0 = 0; a0 < 2; ++a0)
    #pragma unroll
    for (int a1 = 0; a1 < 2; ++a1)
      #pragma unroll
      for (int a2 = 0; a2 < 4; ++a2)
        #pragma unroll
        for (int a3 = 0; a3 < 2; ++a3) acc[a0][a1][a2][a3] = 0.f;
  bf16x8 aF[4][2], bF0[2][2], bF1[2][2];

  // prologue: tile0 (4 halves) + tile1 (A0,B0,A1); drain tile0, keep 6 in flight
  #pragma unroll
  for (int hs = 0; hs < 7; ++hs) STAGE256(hs);
  VM6_;
  __builtin_amdgcn_s_barrier();

  for (int tp = 0; tp < 7; ++tp) {            // tiles 0..13: steady state
    TILE256(2 * tp,     VM6_);
    TILE256(2 * tp + 1, VM6_);
  }
  TILE256(14, VM0_);                          // epilogue drain
  TILE256(15, (void)0);

  // -------- epilogue: bias/relu/resid + coalesced bf16 store via LDS --------
  const int erow = lane >> 2;                 // 0..15
  const int ecc  = lane & 3;                  // 16B chunk 0..3
  char* wb = lds + w * 4096;                  // private 4KB per wave
  float bvv[2][2];
  #pragma unroll
  for (int Ni = 0; Ni < 2; ++Ni)
    #pragma unroll
    for (int jn = 0; jn < 2; ++jn)
      bvv[Ni][jn] = bias ? bias[n0 + Ni * 128 + wn * 32 + jn * 16 + fr] : 0.f;

  #pragma unroll
  for (int Mi = 0; Mi < 2; ++Mi)
    #pragma unroll
    for (int Ni = 0; Ni < 2; ++Ni) {
      #pragma unroll
      for (int i = 0; i < 4; ++i)
        #pragma unroll
        for (int jn = 0; jn < 2; ++jn)
          #pragma unroll
          for (int rr = 0; rr < 4; ++rr) {
            const int row = i * 16 + q * 4 + rr;      // 0..63
            float v = acc[Mi][Ni][i][jn][rr] + bvv[Ni][jn];
            if (RELU) v = fmaxf(v, 0.f);
            const int cp = (jn * 2 + (fr >> 3)) ^ ((row >> 2) & 3);
            *(ushort_t*)(wb + row * 64 + cp * 16 + (fr & 7) * 2) = f2bf(v);
          }
      #pragma unroll
      for (int rd = 0; rd < 4; ++rd) {
        const int row = rd * 16 + erow;
        const int sc = ecc ^ ((row >> 2) & 3);
        bf16x8 seg = *(const bf16x8*)(wb + row * 64 + sc * 16);
        const size_t gaddr = (size_t)(m0 + Mi * 128 + wm * 64 + row) * N
                           + (n0 + Ni * 128 + wn * 32 + ecc * 8);
        if (RESID) {
          const bf16x8 rv = *(const bf16x8*)&resid[gaddr];
          #pragma unroll
          for (int e = 0; e < 8; ++e)
            seg[e] = (short)f2bf(bf2f((ushort_t)seg[e]) + bf2f((ushort_t)rv[e]));
        }
        *(bf16x8*)&outb[gaddr] = seg;
      }
    }
}

// ===========================================================================
// gemm128: 128x256 tile, BK=32, 48KB LDS, 2 blk/CU. Measured best for the
// N=1024 D-GEMMs (tail smoothing at 800-wg grids); worse than gemm256 for
// QKV (LDS-read-bound at 64x64/wave).
// ===========================================================================
#define LBUF_ 24576

#define STG(t_) do { \
    const int lo__ = ((t_) & 1) * LBUF_; \
    gld16(gA  + (t_) * 32, lds + lo__ + dA); \
    gld16(gB0 + (t_) * 32, lds + lo__ + dB0); \
    gld16(gB1 + (t_) * 32, lds + lo__ + dB0 + 1024); \
  } while (0)

#define TIL(t_, STAGES_, VMW_) do { \
    const int lo_ = ((t_) & 1) * LBUF_; \
    _Pragma("unroll") for (int i_ = 0; i_ < 4; ++i_) \
      aF[i_] = *(const bf16x8*)(lds + lo_ + rbA + i_ * 1024 + cR); \
    _Pragma("unroll") for (int j_ = 0; j_ < 4; ++j_) \
      bF[j_] = *(const bf16x8*)(lds + lo_ + rbB + j_ * 1024 + cR); \
    asm volatile("s_waitcnt lgkmcnt(0)" ::: "memory"); \
    __builtin_amdgcn_sched_barrier(0); \
    __builtin_amdgcn_s_setprio(1); \
    _Pragma("unroll") for (int i_ = 0; i_ < 4; ++i_) { \
      acc[i_][0] = MFMA_(aF[i_], bF[0], acc[i_][0]); \
      acc[i_][1] = MFMA_(aF[i_], bF[1], acc[i_][1]); } \
    __builtin_amdgcn_s_setprio(0); \
    __builtin_amdgcn_s_barrier(); \
    __builtin_amdgcn_sched_barrier(0); \
    STAGES_; \
    __builtin_amdgcn_s_setprio(1); \
    _Pragma("unroll") for (int i_ = 0; i_ < 4; ++i_) { \
      acc[i_][2] = MFMA_(aF[i_], bF[2], acc[i_][2]); \
      acc[i_][3] = MFMA_(aF[i_], bF[3], acc[i_][3]); } \
    __builtin_amdgcn_s_setprio(0); \
    VMW_; \
    __builtin_amdgcn_s_barrier(); \
    __builtin_amdgcn_sched_barrier(0); \
  } while (0)

template<int RELU, int RESID>
__global__ __launch_bounds__(512, 4)
void gemm128(const ushort_t* __restrict__ A, const ushort_t* __restrict__ Bw,
             const float* __restrict__ bias,
             ushort_t* __restrict__ outb, const ushort_t* __restrict__ resid,
             int N)
{
  __shared__ __align__(16) char lds[49152];
  const int tid = threadIdx.x;
  const int lane = tid & 63, w = tid >> 6;
  const int fr = lane & 15, q = lane >> 4;
  const int wm = w >> 2, wn = w & 3;          // 2M x 4N wave grid

  // bijective XCD-aware block swizzle (T1, m204 form); nwg % 8 == 0 here
  const int nwg = gridDim.x;
  const int nbx = N >> 8;
  const int qd = nwg >> 3, r8 = nwg & 7;
  const int xcd = blockIdx.x & 7, idx = blockIdx.x >> 3;
  const int wg = (xcd < r8 ? xcd * (qd + 1) : r8 * (qd + 1) + (xcd - r8) * qd) + idx;
  const int m0 = (wg / nbx) * 128, n0 = (wg % nbx) * 256;

  const int xc = (lane & 3) ^ ((lane >> 3) & 3);
  const ushort_t* gA  = A  + (size_t)(m0 + w * 16 + (lane >> 2)) * 1024 + xc * 8;
  const ushort_t* gB0 = Bw + (size_t)(n0 + w * 32 + (lane >> 2)) * 1024 + xc * 8;
  const ushort_t* gB1 = gB0 + 16 * 1024;
  const int dA  = w * 1024;
  const int dB0 = 8192 + w * 2048;

  const int cR  = fr * 64 + ((q ^ ((fr >> 1) & 3)) << 4);
  const int rbA = wm * 4096;          // + i*1024
  const int rbB = 8192 + wn * 4096;   // + j*1024

  f32x4 acc[4][4];
  #pragma unroll
  for (int i = 0; i < 4; ++i)
    #pragma unroll
    for (int j = 0; j < 4; ++j) acc[i][j] = 0.f;
  bf16x8 aF[4], bF[4];

  STG(0); STG(1);
  VM3_;
  __builtin_amdgcn_s_barrier();
  __builtin_amdgcn_sched_barrier(0);

  #pragma unroll
  for (int t = 0; t < 30; ++t) TIL(t, STG(t + 2), VM3_);
  TIL(30, (void)0, VM0_);             // drain: tile31 data fully landed
  TIL(31, (void)0, (void)0);
  __syncthreads();                    // LDS reuse for epilogue staging

  const int erow = lane >> 2;         // 0..15
  const int ecc  = lane & 3;          // 16B chunk 0..3
  char* wb = lds + w * 4096;          // private 4KB per wave
  float bvv[2][2];
  #pragma unroll
  for (int jh = 0; jh < 2; ++jh)
    #pragma unroll
    for (int jn = 0; jn < 2; ++jn)
      bvv[jh][jn] = bias ? bias[n0 + wn * 64 + jh * 32 + jn * 16 + fr] : 0.f;

  #pragma unroll
  for (int jh = 0; jh < 2; ++jh) {    // column halves (32 cols each)
    #pragma unroll
    for (int i = 0; i < 4; ++i)
      #pragma unroll
      for (int jn = 0; jn < 2; ++jn)
        #pragma unroll
        for (int rr = 0; rr < 4; ++rr) {
          const int row = i * 16 + q * 4 + rr;      // 0..63
          float v = acc[i][jh * 2 + jn][rr] + bvv[jh][jn];
          if (RELU) v = fmaxf(v, 0.f);
          const int cp = (jn * 2 + (fr >> 3)) ^ ((row >> 2) & 3);
          *(ushort_t*)(wb + row * 64 + cp * 16 + (fr & 7) * 2) = f2bf(v);
        }
    #pragma unroll
    for (int rd = 0; rd < 4; ++rd) {
      const int row = rd * 16 + erow;
      const int sc = ecc ^ ((row >> 2) & 3);
      bf16x8 seg = *(const bf16x8*)(wb + row * 64 + sc * 16);
      const size_t gaddr = (size_t)(m0 + wm * 64 + row) * N
                         + (n0 + wn * 64 + jh * 32 + ecc * 8);
      if (RESID) {
        const bf16x8 rv = *(const bf16x8*)&resid[gaddr];
        #pragma unroll
        for (int e = 0; e < 8; ++e)
          seg[e] = (short)f2bf(bf2f((ushort_t)seg[e]) + bf2f((ushort_t)rv[e]));
      }
      *(bf16x8*)&outb[gaddr] = seg;
    }
  }
}

// ---------------------------------------------------------------------------
// Legacy 128x128 GEMM — retained ONLY for the final split-K fp32-partial GEMM.
// ---------------------------------------------------------------------------
template<int RELU, int RESID, int OBF, int OF32>
__global__ __launch_bounds__(256)
void gemm_nt(const ushort_t* __restrict__ A, const ushort_t* __restrict__ Bw,
             const float* __restrict__ bias,
             ushort_t* outb, float* outf, const ushort_t* __restrict__ resid,
             int M, int N, int K, int ksteps)
{
  __shared__ ushort_t lds[16384];
  ushort_t* lsA = lds;
  ushort_t* lsB = lds + 8192;
  const int tid = threadIdx.x, lane = tid & 63, wave = tid >> 6;
  const int fr = lane & 15, q = lane >> 4;
  const int m0 = blockIdx.y * 128, n0 = blockIdx.x * 128;
  const int wm = (wave >> 1) * 64, wn = (wave & 1) * 64;
  const int kbase = blockIdx.z * ksteps * 64;

  const ushort_t* Ab = A + (size_t)m0 * K + kbase;
  const ushort_t* Bb = Bw + (size_t)n0 * K + kbase;

  const int kg = (lane & 7) ^ (lane >> 3);
  const ushort_t* gaA = Ab + (size_t)(lane >> 3) * K + kg * 8;
  const ushort_t* gaB = Bb + (size_t)(lane >> 3) * K + kg * 8;

  f32x4 acc[4][4];
  #pragma unroll
  for (int i = 0; i < 4; i++)
    #pragma unroll
    for (int j = 0; j < 4; j++) acc[i][j] = 0.f;

  int rowA[4], rowB[4];
  #pragma unroll
  for (int t = 0; t < 4; t++) {
    rowA[t] = (wm + t * 16 + fr) * 64;
    rowB[t] = (wn + t * 16 + fr) * 64;
  }
  const int sl0 = ((0 * 4 + q) ^ (fr & 7)) * 8;
  const int sl1 = ((1 * 4 + q) ^ (fr & 7)) * 8;

  for (int ks = 0; ks < ksteps; ks++) {
    __syncthreads();
    #pragma unroll
    for (int u = 0; u < 4; u++) {
      const int i = wave * 4 + u;
      gld16(gaA + ks * 64 + (size_t)i * 8 * K, lsA + i * 512);
      gld16(gaB + ks * 64 + (size_t)i * 8 * K, lsB + i * 512);
    }
    __syncthreads();
    #pragma unroll
    for (int s = 0; s < 2; s++) {
      const int sl = s ? sl1 : sl0;
      bf16x8 af[4], bfv[4];
      #pragma unroll
      for (int t = 0; t < 4; t++) {
        af[t]  = *(const bf16x8*)(lsA + rowA[t] + sl);
        bfv[t] = *(const bf16x8*)(lsB + rowB[t] + sl);
      }
      #pragma unroll
      for (int i = 0; i < 4; i++)
        #pragma unroll
        for (int j = 0; j < 4; j++)
          acc[i][j] = MFMA_(af[i], bfv[j], acc[i][j]);
    }
  }

  if (OF32) {  // fp32 split-K partial (final GEMM only; small output)
    float* po = outf + (size_t)blockIdx.z * M * N;
    #pragma unroll
    for (int i = 0; i < 4; i++) {
      const int rb = m0 + wm + i * 16 + q * 4;
      #pragma unroll
      for (int j = 0; j < 4; j++) {
        const int col = n0 + wn + j * 16 + fr;
        #pragma unroll
        for (int rr = 0; rr < 4; rr++)
          po[(size_t)(rb + rr) * N + col] = acc[i][j][rr];
      }
    }
  }
}

// ---------------------------------------------------------------------------
// Fused attention: one block per (head, batch). qkv:[BT,3072] bf16.
// R11: forced unroll on c/mt loops (static cacc indexing, rule #20 guard).
// ---------------------------------------------------------------------------
#define KST 136   // Kls row stride (bf16): 272B rows, 2-way banks (free)
#define VST 120   // Vt row stride (bf16)
#define PST 120   // Pls row stride (bf16)

__global__ __launch_bounds__(256)
void attn_kernel(const ushort_t* __restrict__ qkv, ushort_t* __restrict__ ctx)
{
  __shared__ ushort_t Kls[112 * KST];  // 30464 B
  __shared__ ushort_t Vt[128 * VST];   // 30720 B
  __shared__ ushort_t Pls[64 * PST];   // 15360 B  (total 76544 B -> 2 blk/CU)
  const int tid = threadIdx.x, lane = tid & 63, wave = tid >> 6;
  const int fr = lane & 15, q = lane >> 4;
  const int hh = blockIdx.x, bb = blockIdx.y;
  const size_t base = (size_t)bb * T_ * DQ_;
  const ushort_t* Qb = qkv + base + hh * HD_;
  const ushort_t* Kb = qkv + base + D_ + hh * HD_;
  const ushort_t* Vb = qkv + base + 2 * D_ + hh * HD_;

  for (int e = tid; e < 1600; e += 256) {
    const int j = e >> 4, kc = e & 15;
    *(bf16x8*)&Kls[j * KST + kc * 8] = *(const bf16x8*)(Kb + (size_t)j * DQ_ + kc * 8);
  }
  for (int e = tid; e < 12 * KST; e += 256) Kls[100 * KST + e] = 0;
  for (int e = tid; e < 1600; e += 256) {
    const int j = e >> 4, dc = e & 15;
    const bf16x8 v = *(const bf16x8*)(Vb + (size_t)j * DQ_ + dc * 8);
    #pragma unroll
    for (int u = 0; u < 8; u++) Vt[(dc * 8 + u) * VST + j] = (ushort_t)v[u];
  }
  for (int e = tid; e < 128 * 12; e += 256) {
    const int d = e / 12, j = e - d * 12;
    Vt[d * VST + 100 + j] = 0;
  }
  __syncthreads();

  #pragma unroll
  for (int c = 0; c < 2; c++) {
    if (c) __syncthreads();
    const int it  = c * 4 + wave;
    const bool wlive = (it < 7);
    const int itc = wlive ? it : 6;
    const int qrow = min(itc * 16 + fr, T_ - 1);
    bf16x8 aq[4];
    #pragma unroll
    for (int ks = 0; ks < 4; ks++)
      aq[ks] = *(const bf16x8*)(Qb + (size_t)qrow * DQ_ + ks * 32 + q * 8);
    f32x4 sacc[7];
    #pragma unroll
    for (int jt = 0; jt < 7; jt++) sacc[jt] = 0.f;
    #pragma unroll
    for (int ks = 0; ks < 4; ks++) {
      const int kk = ks * 32 + q * 8;
      #pragma unroll
      for (int jt = 0; jt < 7; jt++) {
        const bf16x8 kb = *(const bf16x8*)&Kls[(jt * 16 + fr) * KST + kk];
        sacc[jt] = MFMA_(aq[ks], kb, sacc[jt]);
      }
    }
    ushort_t pbf[7][4];
    #pragma unroll
    for (int rr = 0; rr < 4; rr++) {
      float sv[7];
      float mx = -1e30f;
      #pragma unroll
      for (int jt = 0; jt < 7; jt++) {
        float s = sacc[jt][rr] * SCALE_;
        if (jt == 6 && fr >= 4) s = -1e30f;
        sv[jt] = s;
        mx = fmaxf(mx, s);
      }
      mx = fmaxf(mx, __shfl_xor(mx, 1));
      mx = fmaxf(mx, __shfl_xor(mx, 2));
      mx = fmaxf(mx, __shfl_xor(mx, 4));
      mx = fmaxf(mx, __shfl_xor(mx, 8));
      float sum = 0.f;
      #pragma unroll
      for (int jt = 0; jt < 7; jt++) { sv[jt] = __expf(sv[jt] - mx); sum += sv[jt]; }
      sum += __shfl_xor(sum, 1);
      sum += __shfl_xor(sum, 2);
      sum += __shfl_xor(sum, 4);
      sum += __shfl_xor(sum, 8);
      const float inv = 1.f / sum;
      #pragma unroll
      for (int jt = 0; jt < 7; jt++) pbf[jt][rr] = f2bf(sv[jt] * inv);
    }
    if (wlive) {
      #pragma unroll
      for (int jt = 0; jt < 7; jt++)
        #pragma unroll
        for (int rr = 0; rr < 4; rr++)
          Pls[(wave * 16 + q * 4 + rr) * PST + jt * 16 + fr] = pbf[jt][rr];
    }
    __syncthreads();
    const int mtc = (c == 0) ? 4 : 3;
    f32x4 cacc[4][2];
    #pragma unroll
    for (int i = 0; i < 4; i++) { cacc[i][0] = 0.f; cacc[i][1] = 0.f; }
    #pragma unroll
    for (int ks = 0; ks < 4; ks++) {
      const int kk = ks * 32 + q * 8;
      const bool live = (ks < 3) || (q < 2);
      bf16x8 v0 = 0, v1 = 0;
      if (live) {
        v0 = *(const bf16x8*)&Vt[((wave * 2 + 0) * 16 + fr) * VST + kk];
        v1 = *(const bf16x8*)&Vt[((wave * 2 + 1) * 16 + fr) * VST + kk];
      }
      #pragma unroll
      for (int mt = 0; mt < 4; mt++) {
        if (mt < mtc) {
          bf16x8 a = 0;
          if (live) a = *(const bf16x8*)&Pls[(mt * 16 + fr) * PST + kk];
          cacc[mt][0] = MFMA_(a, v0, cacc[mt][0]);
          cacc[mt][1] = MFMA_(a, v1, cacc[mt][1]);
        }
      }
    }
    #pragma unroll
    for (int mt = 0; mt < 4; mt++) {
      if (mt < mtc) {
        #pragma unroll
        for (int nn = 0; nn < 2; nn++) {
          const int col = hh * HD_ + (wave * 2 + nn) * 16 + fr;
          #pragma unroll
          for (int rr = 0; rr < 4; rr++) {
            const int r = c * 64 + mt * 16 + q * 4 + rr;
            if (r < T_)
              ctx[(size_t)(bb * T_ + r) * D_ + col] = f2bf(cacc[mt][nn][rr]);
          }
        }
      }
    }
  }
}

// ---------------------------------------------------------------------------
// LayerNorm: bf16 in -> bf16 out (fp32 stats). One block per row.
// ---------------------------------------------------------------------------
__global__ __launch_bounds__(256)
void ln_kernel(const ushort_t* __restrict__ in, ushort_t* __restrict__ outb,
               const float* __restrict__ g, const float* __restrict__ bta)
{
  const int row = blockIdx.x, tid = threadIdx.x;
  const int c4 = tid * 4;
  const ushort4 uv = *(const ushort4*)(in + (size_t)row * D_ + c4);
  const float v0 = bf2f(uv.x), v1 = bf2f(uv.y), v2 = bf2f(uv.z), v3 = bf2f(uv.w);
  float s  = v0 + v1 + v2 + v3;
  float ss = v0*v0 + v1*v1 + v2*v2 + v3*v3;
  #pragma unroll
  for (int o = 1; o < 64; o <<= 1) {
    s  += __shfl_xor(s, o);
    ss += __shfl_xor(ss, o);
  }
  __shared__ float red[8];
  const int lane = tid & 63, wave = tid >> 6;
  if (lane == 0) { red[wave] = s; red[4 + wave] = ss; }
  __syncthreads();
  s  = red[0] + red[1] + red[2] + red[3];
  ss = red[4] + red[5] + red[6] + red[7];
  const float mean = s * (1.f / D_);
  const float var  = ss * (1.f / D_) - mean * mean;
  const float rstd = rsqrtf(var + 1e-5f);
  const float4 gv = *(const float4*)(g + c4);
  const float4 bv = *(const float4*)(bta + c4);
  ushort4 ob = { f2bf((v0 - mean) * rstd * gv.x + bv.x),
                 f2bf((v1 - mean) * rstd * gv.y + bv.y),
                 f2bf((v2 - mean) * rstd * gv.z + bv.z),
                 f2bf((v3 - mean) * rstd * gv.w + bv.w) };
  *(ushort4*)(outb + (size_t)row * D_ + c4) = ob;
}

// ---------------------------------------------------------------------------
// PE table: pe[t][d] for t<T, d<D. 100 blocks x 256 thr; 512 sincos pairs/row.
// ---------------------------------------------------------------------------
__global__ __launch_bounds__(256)
void pe_init(float* __restrict__ pe)
{
  const int t = blockIdx.x;
  #pragma unroll
  for (int j = 0; j < 2; ++j) {
    const int k = threadIdx.x + j * 256;        // 0..511
    const float ang = (float)t * expf((float)k * -0.017988946039015984f);
    float s, c;
    sincosf(ang, &s, &c);
    pe[t * D_ + 2 * k]     = s;
    pe[t * D_ + 2 * k + 1] = c;
  }
}

// ---------------------------------------------------------------------------
// Embedding: h = x@Wi + bi + pe[t,:] -> bf16. One block per token row.
// ---------------------------------------------------------------------------
__global__ __launch_bounds__(256)
void embed_kernel(const float* __restrict__ x, const float* __restrict__ Wi,
                  const float* __restrict__ bi, const float* __restrict__ pe,
                  ushort_t* __restrict__ hbf)
{
  const int row = blockIdx.x;
  const int t = row % T_;
  const int c = threadIdx.x * 4;
  float xv[6];
  #pragma unroll
  for (int i = 0; i < 6; i++) xv[i] = x[row * 6 + i];
  const float4 pv = *(const float4*)(pe + t * D_ + c);
  const float4 bv = *(const float4*)(bi + c);
  float a0 = bv.x + pv.x, a1 = bv.y + pv.y, a2 = bv.z + pv.z, a3 = bv.w + pv.w;
  #pragma unroll
  for (int i = 0; i < 6; i++) {
    const float4 wv = *(const float4*)(Wi + i * D_ + c);
    a0 += xv[i] * wv.x; a1 += xv[i] * wv.y;
    a2 += xv[i] * wv.z; a3 += xv[i] * wv.w;
  }
  ushort4 ob = { f2bf(a0), f2bf(a1), f2bf(a2), f2bf(a3) };
  *(ushort4*)(hbf + (size_t)row * D_ + c) = ob;
}

// All weight tensors -> bf16 in one launch.
#define NQW (L_*DQ_*D_)   // 12582912
#define NDW (L_*D_*D_)    //  4194304
__global__ void cvt_all(const float* __restrict__ qw, const float* __restrict__ ow,
                        const float* __restrict__ f1, const float* __restrict__ f2,
                        ushort_t* wq, ushort_t* wo, ushort_t* w1, ushort_t* w2)
{
  const size_t i = ((size_t)blockIdx.x * 256 + threadIdx.x) * 4;
  const float* s; ushort_t* d; size_t off;
  if (i < NQW)                { s = qw; d = wq; off = i; }
  else if (i < NQW + NDW)     { s = ow; d = wo; off = i - NQW; }
  else if (i < NQW + 2*NDW)   { s = f1; d = w1; off = i - NQW - NDW; }
  else                        { s = f2; d = w2; off = i - NQW - 2*NDW; }
  const float4 v = *(const float4*)(s + off);
  ushort4 o = { f2bf(v.x), f2bf(v.y), f2bf(v.z), f2bf(v.w) };
  *(ushort4*)(d + off) = o;
}

// Wo [KFIN,256] fp32 -> Wot [256,KFIN] bf16
__global__ __launch_bounds__(256)
void transpose_wo(const float* __restrict__ src, ushort_t* __restrict__ dst)
{
  __shared__ float tile[64][65];
  const int k0 = blockIdx.x * 64, n0 = blockIdx.y * 64;
  const int tc = threadIdx.x & 63, tr = threadIdx.x >> 6;
  #pragma unroll
  for (int i = 0; i < 16; i++) {
    const int r = i * 4 + tr;
    tile[r][tc] = src[(size_t)(k0 + r) * OUT_ + n0 + tc];
  }
  __syncthreads();
  #pragma unroll
  for (int i = 0; i < 16; i++) {
    const int n = i * 4 + tr;
    dst[(size_t)(n0 + n) * KFIN_ + k0 + tc] = f2bf(tile[tc][n]);
  }
}

__global__ void reduce_final(const float* __restrict__ part,
                             const float* __restrict__ bo, float* __restrict__ out)
{
  const int i = blockIdx.x * 256 + threadIdx.x;   // 65536 outputs
  float s = bo[i & (OUT_ - 1)];
  for (int z = 0; z < KSPLIT_; z++) s += part[(size_t)z * OUT_ * OUT_ + i];
  out[i] = s;
}

// ---------------------------------------------------------------------------
extern "C" void kernel_launch(void* const* d_in, const int* in_sizes, int n_in,
                              void* d_out, int out_size, void* d_ws, size_t ws_size,
                              hipStream_t stream)
{
  (void)in_sizes; (void)n_in; (void)out_size; (void)ws_size;
  const float* x     = (const float*)d_in[0];
  const float* Wi    = (const float*)d_in[1];
  const float* bi    = (const float*)d_in[2];
  const float* qkv_w = (const float*)d_in[3];
  const float* qkv_b = (const float*)d_in[4];
  const float* out_w = (const float*)d_in[5];
  const float* out_b = (const float*)d_in[6];
  const float* ff1_w = (const float*)d_in[7];
  const float* ff1_b = (const float*)d_in[8];
  const float* ff2_w = (const float*)d_in[9];
  const float* ff2_b = (const float*)d_in[10];
  const float* ln1_g = (const float*)d_in[11];
  const float* ln1_b = (const float*)d_in[12];
  const float* ln2_g = (const float*)d_in[13];
  const float* ln2_b = (const float*)d_in[14];
  const float* Wo    = (const float*)d_in[15];
  const float* bo    = (const float*)d_in[16];
  float* out = (float*)d_out;

  // workspace layout — ~313 MiB peak
  char* p = (char*)d_ws;
  ushort_t* hbf  = (ushort_t*)p; p += (size_t)BT_ * D_ * 2;     //  52.4 MB
  ushort_t* qkvb = (ushort_t*)p; p += (size_t)BT_ * DQ_ * 2;    // 157.3 MB
  ushort_t* ctxb = (ushort_t*)p; p += (size_t)BT_ * D_ * 2;     //  52.4 MB
  ushort_t* wq   = (ushort_t*)p; p += (size_t)NQW * 2;          //  25.2 MB
  ushort_t* wo   = (ushort_t*)p; p += (size_t)NDW * 2;          //   8.4 MB
  ushort_t* w1   = (ushort_t*)p; p += (size_t)NDW * 2;          //   8.4 MB
  ushort_t* w2   = (ushort_t*)p; p += (size_t)NDW * 2;          //   8.4 MB
  float*    pe   = (float*)p;    p += (size_t)T_ * D_ * 4;      //   0.4 MB
  ushort_t* ffact = qkvb;                         // qkv dead after attention
  ushort_t* sum   = qkvb + (size_t)BT_ * D_;      // pre-LN sum (slot 1)
  ushort_t* wot   = ctxb;                         // ctx dead after last out-proj
  float*    part  = (float*)qkvb;                 // final split-K partials

  cvt_all<<<dim3((NQW + 3*NDW) / 1024), 256, 0, stream>>>(
      qkv_w, out_w, ff1_w, ff2_w, wq, wo, w1, w2);
  pe_init<<<dim3(T_), 256, 0, stream>>>(pe);
  embed_kernel<<<dim3(BT_), 256, 0, stream>>>(x, Wi, bi, pe, hbf);

  for (int i = 0; i < L_; i++) {
    // qkv = h @ qkv_w^T + b  -> bf16   (gemm256: measured 163.6us)
    gemm256<0,0><<<dim3((BT_/256)*(DQ_/256)), 512, 0, stream>>>(
        hbf, wq + (size_t)i * DQ_ * D_, qkv_b + i * DQ_, qkvb, nullptr, DQ_);
    attn_kernel<<<dim3(H_, B_), 256, 0, stream>>>(qkvb, ctxb);
    // sum = ctx @ out_w^T + b + h   (gemm128: 800 wgs, 2 blk/CU)
    gemm128<0,1><<<dim3((BT_/128)*(D_/256)), 512, 0, stream>>>(
        ctxb, wo + (size_t)i * D_ * D_, out_b + i * D_, sum, hbf, D_);
    ln_kernel<<<dim3(BT_), 256, 0, stream>>>(sum, hbf, ln1_g + i * D_, ln1_b + i * D_);
    // ff = relu(h @ ff1^T + b) -> bf16
    gemm128<1,0><<<dim3((BT_/128)*(D_/256)), 512, 0, stream>>>(
        hbf, w1 + (size_t)i * D_ * D_, ff1_b + i * D_, ffact, nullptr, D_);
    // sum = ff @ ff2^T + b + h   (bf16)
    gemm128<0,1><<<dim3((BT_/128)*(D_/256)), 512, 0, stream>>>(
        ffact, w2 + (size_t)i * D_ * D_, ff2_b + i * D_, sum, hbf, D_);
    ln_kernel<<<dim3(BT_), 256, 0, stream>>>(sum, hbf, ln2_g + i * D_, ln2_b + i * D_);
  }

  // final: out = h.reshape(256,102400) @ Wo + bo   (split-K partials + reduce)
  transpose_wo<<<dim3(KFIN_/64, OUT_/64), 256, 0, stream>>>(Wo, wot);
  gemm_nt<0,0,0,1><<<dim3(OUT_/128, OUT_/128, KSPLIT_), 256, 0, stream>>>(
      hbf, wot, nullptr, nullptr, part, nullptr,
      OUT_, OUT_, KFIN_, KFIN_ / (KSPLIT_ * 64));
  reduce_final<<<dim3(OUT_ * OUT_ / 256), 256, 0, stream>>>(part, bo, out);
}

// Round 7
// 2170.883 us; speedup vs baseline: 1.0966x; 1.0135x over previous
//
#include <hip/hip_runtime.h>

// TrajectoryTransformer fused bf16-MFMA implementation for MI355X (gfx950).
// B=256 T=100 IN=6 D=1024 H=8 HD=128 L=4 OUT=256.
// R7: embed de-transcendentalized (PE table).
// R11: HYBRID — gemm256 for QKV (measured 160us), gemm128 for D-GEMMs;
//      attn static-indexing guard (rule #20) recovered ~100us.
// R12: attn swapped-QK^T (compute mfma(K,Q) = S^T, query = lane&15) =>
//      softmax row is LANE-LOCAL: 27 VALU + 2 shfl (xor16/32) replaces
//      32 dependent shfl+wait ops per wave per chunk. Mask/keys re-derived:
//      key = jt*16+q*4+rr; masked iff jt==6 && q*4+rr>=4 (keys 100..111).

#define B_    256
#define T_    100
#define D_    1024
#define H_    8
#define HD_   128
#define L_    4
#define BT_   25600          // B*T
#define DQ_   3072           // 3*D
#define OUT_  256
#define KFIN_ 102400         // T*D
#define KSPLIT_ 32
#define SCALE_ 0.08838834764831845f  // 1/sqrt(128)

typedef unsigned short ushort_t;
typedef __attribute__((ext_vector_type(8))) short bf16x8;   // 8 bf16 (4 VGPRs)
typedef __attribute__((ext_vector_type(4))) float f32x4;    // MFMA C/D

__device__ inline ushort_t f2bf(float f) {   // RNE fp32 -> bf16
  unsigned u = __float_as_uint(f);
  u += 0x7FFFu + ((u >> 16) & 1u);
  return (ushort_t)(u >> 16);
}
__device__ inline float bf2f(ushort_t u) {
  return __uint_as_float((unsigned)u << 16);
}

// async global->LDS, 16B per lane; LDS dest is wave-uniform base + lane*16
__device__ inline void gld16(const void* g, void* l) {
  __builtin_amdgcn_global_load_lds(
      (__attribute__((address_space(1))) unsigned int*)(size_t)g,
      (__attribute__((address_space(3))) unsigned int*)l, 16, 0, 0);
}

#define MFMA_(a, b, c) __builtin_amdgcn_mfma_f32_16x16x32_bf16(a, b, c, 0, 0, 0)

#define VM6_ asm volatile("s_waitcnt vmcnt(6)" ::: "memory")
#define VM3_ asm volatile("s_waitcnt vmcnt(3)" ::: "memory")
#define VM0_ asm volatile("s_waitcnt vmcnt(0)" ::: "memory")

// ===========================================================================
// gemm256: 256x256 tile, BK=64, 16 K-tiles, 8 waves (2M x 4N), per-wave
// 128x64. 8-phase counted-vmcnt schedule, 128KB LDS dbuf, 1 blk/CU.
// Measured (R6/R11): QKV ~160us, MfmaUtil 44%. Best for large-grid GEMMs.
// ===========================================================================
#define GBUF_ 65536
#define GBOF_ 32768

#define STAGE256(hs_) do { \
    const int hs__ = (hs_); \
    if (hs__ < 64) { \
      const int tt__ = hs__ >> 2, id__ = hs__ & 3; \
      const int half__ = id__ >> 1; \
      const int bo__ = (tt__ & 1) * GBUF_ + half__ * 16384 + wsl \
                     + ((id__ & 1) ? GBOF_ : 0); \
      const ushort_t* s__ = ((id__ & 1) ? gB : gA) \
                     + (size_t)(half__ * 128) * 1024 + tt__ * 64; \
      gld16(s__, lds + bo__); \
      gld16(s__ + 8 * 1024, lds + bo__ + 1024); \
    } \
  } while (0)

#define LDA256(Mi) do { \
    const char* ba__ = lds + ldsoff + (Mi) * 16384 + rbA; \
    _Pragma("unroll") for (int i_ = 0; i_ < 4; ++i_) { \
      aF[i_][0] = *(const bf16x8*)(ba__ + i_ * 2048 + c0); \
      aF[i_][1] = *(const bf16x8*)(ba__ + i_ * 2048 + c1); \
    } \
  } while (0)

#define LDB256(Ni, BF) do { \
    const char* bb__ = lds + ldsoff + (Ni) * 16384 + rbB; \
    _Pragma("unroll") for (int j_ = 0; j_ < 2; ++j_) { \
      BF[j_][0] = *(const bf16x8*)(bb__ + j_ * 2048 + c0); \
      BF[j_][1] = *(const bf16x8*)(bb__ + j_ * 2048 + c1); \
    } \
  } while (0)

#define MM256(Mi, Ni, BF) do { \
    _Pragma("unroll") for (int i_ = 0; i_ < 4; ++i_) \
      _Pragma("unroll") for (int j_ = 0; j_ < 2; ++j_) { \
        acc[Mi][Ni][i_][j_] = MFMA_(aF[i_][0], BF[j_][0], acc[Mi][Ni][i_][j_]); \
        acc[Mi][Ni][i_][j_] = MFMA_(aF[i_][1], BF[j_][1], acc[Mi][Ni][i_][j_]); \
      } \
  } while (0)

#define PH256(t, p, LOADS, Mi, Ni, BF, VM) do { \
    LOADS; \
    STAGE256(7 + 4 * (t) + (p)); \
    __builtin_amdgcn_s_barrier(); \
    asm volatile("s_waitcnt lgkmcnt(0)" ::: "memory"); \
    __builtin_amdgcn_sched_barrier(0); \
    __builtin_amdgcn_s_setprio(1); \
    MM256(Mi, Ni, BF); \
    __builtin_amdgcn_s_setprio(0); \
    VM; \
    __builtin_amdgcn_s_barrier(); \
  } while (0)

#define TILE256(t, VM) do { \
    const int ldsoff = ((t) & 1) * GBUF_; \
    PH256(t, 0, { LDA256(0); LDB256(0, bF0); }, 0, 0, bF0, (void)0); \
    PH256(t, 1, { LDB256(1, bF1); },            0, 1, bF1, (void)0); \
    PH256(t, 2, { LDA256(1); },                 1, 1, bF1, (void)0); \
    PH256(t, 3, { },                            1, 0, bF0, VM); \
  } while (0)

template<int RELU, int RESID>
__global__ __launch_bounds__(512, 1)
void gemm256(const ushort_t* __restrict__ A, const ushort_t* __restrict__ Bw,
             const float* __restrict__ bias,
             ushort_t* __restrict__ outb, const ushort_t* __restrict__ resid,
             int N)
{
  __shared__ char lds[131072];
  const int tid = threadIdx.x;
  const int lane = tid & 63, w = tid >> 6;
  const int fr = lane & 15, q = lane >> 4;
  const int wm = w >> 2, wn = w & 3;          // 2 x 4 wave grid

  // bijective XCD-aware block swizzle (T1, m204 form)
  const int nwg = gridDim.x;
  const int nbx = N >> 8;
  const int qd = nwg >> 3, r8 = nwg & 7;
  const int xcd = blockIdx.x & 7, idx = blockIdx.x >> 3;
  const int wg = (xcd < r8 ? xcd * (qd + 1) : r8 * (qd + 1) + (xcd - r8) * qd) + idx;
  const int m0 = (wg / nbx) * 256, n0 = (wg % nbx) * 256;

  // staging: wave w covers 16 rows (w*16 + j*8 + lane/8) of each 128-row half
  const int lr8 = lane >> 3;
  const int xch = (lane & 7) ^ lr8;           // pre-swizzled source chunk
  const ushort_t* gA = A  + (size_t)(m0 + w * 16 + lr8) * 1024 + xch * 8;
  const ushort_t* gB = Bw + (size_t)(n0 + w * 16 + lr8) * 1024 + xch * 8;
  const int wsl = w * 2048;                   // LDS dest slice (2 x 1KB issues)

  // read addressing (swizzled chunks; row&7 == fr&7 for all fragment rows)
  const int c0 = (q ^ (fr & 7)) * 16;         // kk=0
  const int c1 = ((4 + q) ^ (fr & 7)) * 16;   // kk=1
  const int rbA = (wm * 64 + fr) * 128;
  const int rbB = GBOF_ + (wn * 32 + fr) * 128;

  f32x4 acc[2][2][4][2];
  #pragma unroll
  for (int a0 = 0; a0 < 2; ++a0)
    #pragma unroll
    for (int a1 = 0; a1 < 2; ++a1)
      #pragma unroll
      for (int a2 = 0; a2 < 4; ++a2)
        #pragma unroll
        for (int a3 = 0; a3 < 2; ++a3) acc[a0][a1][a2][a3] = 0.f;
  bf16x8 aF[4][2], bF0[2][2], bF1[2][2];

  // prologue: tile0 (4 halves) + tile1 (A0,B0,A1); drain tile0, keep 6 in flight
  #pragma unroll
  for (int hs = 0; hs < 7; ++hs) STAGE256(hs);
  VM6_;
  __builtin_amdgcn_s_barrier();

  for (int tp = 0; tp < 7; ++tp) {            // tiles 0..13: steady state
    TILE256(2 * tp,     VM6_);
    TILE256(2 * tp + 1, VM6_);
  }
  TILE256(14, VM0_);                          // epilogue drain
  TILE256(15, (void)0);

  // -------- epilogue: bias/relu/resid + coalesced bf16 store via LDS --------
  const int erow = lane >> 2;                 // 0..15
  const int ecc  = lane & 3;                  // 16B chunk 0..3
  char* wb = lds + w * 4096;                  // private 4KB per wave
  float bvv[2][2];
  #pragma unroll
  for (int Ni = 0; Ni < 2; ++Ni)
    #pragma unroll
    for (int jn = 0; jn < 2; ++jn)
      bvv[Ni][jn] = bias ? bias[n0 + Ni * 128 + wn * 32 + jn * 16 + fr] : 0.f;

  #pragma unroll
  for (int Mi = 0; Mi < 2; ++Mi)
    #pragma unroll
    for (int Ni = 0; Ni < 2; ++Ni) {
      #pragma unroll
      for (int i = 0; i < 4; ++i)
        #pragma unroll
        for (int jn = 0; jn < 2; ++jn)
          #pragma unroll
          for (int rr = 0; rr < 4; ++rr) {
            const int row = i * 16 + q * 4 + rr;      // 0..63
            float v = acc[Mi][Ni][i][jn][rr] + bvv[Ni][jn];
            if (RELU) v = fmaxf(v, 0.f);
            const int cp = (jn * 2 + (fr >> 3)) ^ ((row >> 2) & 3);
            *(ushort_t*)(wb + row * 64 + cp * 16 + (fr & 7) * 2) = f2bf(v);
          }
      #pragma unroll
      for (int rd = 0; rd < 4; ++rd) {
        const int row = rd * 16 + erow;
        const int sc = ecc ^ ((row >> 2) & 3);
        bf16x8 seg = *(const bf16x8*)(wb + row * 64 + sc * 16);
        const size_t gaddr = (size_t)(m0 + Mi * 128 + wm * 64 + row) * N
                           + (n0 + Ni * 128 + wn * 32 + ecc * 8);
        if (RESID) {
          const bf16x8 rv = *(const bf16x8*)&resid[gaddr];
          #pragma unroll
          for (int e = 0; e < 8; ++e)
            seg[e] = (short)f2bf(bf2f((ushort_t)seg[e]) + bf2f((ushort_t)rv[e]));
        }
        *(bf16x8*)&outb[gaddr] = seg;
      }
    }
}

// ===========================================================================
// gemm128: 128x256 tile, BK=32, 48KB LDS, 2 blk/CU. Measured best for the
// N=1024 D-GEMMs; worse than gemm256 for QKV.
// ===========================================================================
#define LBUF_ 24576

#define STG(t_) do { \
    const int lo__ = ((t_) & 1) * LBUF_; \
    gld16(gA  + (t_) * 32, lds + lo__ + dA); \
    gld16(gB0 + (t_) * 32, lds + lo__ + dB0); \
    gld16(gB1 + (t_) * 32, lds + lo__ + dB0 + 1024); \
  } while (0)

#define TIL(t_, STAGES_, VMW_) do { \
    const int lo_ = ((t_) & 1) * LBUF_; \
    _Pragma("unroll") for (int i_ = 0; i_ < 4; ++i_) \
      aF[i_] = *(const bf16x8*)(lds + lo_ + rbA + i_ * 1024 + cR); \
    _Pragma("unroll") for (int j_ = 0; j_ < 4; ++j_) \
      bF[j_] = *(const bf16x8*)(lds + lo_ + rbB + j_ * 1024 + cR); \
    asm volatile("s_waitcnt lgkmcnt(0)" ::: "memory"); \
    __builtin_amdgcn_sched_barrier(0); \
    __builtin_amdgcn_s_setprio(1); \
    _Pragma("unroll") for (int i_ = 0; i_ < 4; ++i_) { \
      acc[i_][0] = MFMA_(aF[i_], bF[0], acc[i_][0]); \
      acc[i_][1] = MFMA_(aF[i_], bF[1], acc[i_][1]); } \
    __builtin_amdgcn_s_setprio(0); \
    __builtin_amdgcn_s_barrier(); \
    __builtin_amdgcn_sched_barrier(0); \
    STAGES_; \
    __builtin_amdgcn_s_setprio(1); \
    _Pragma("unroll") for (int i_ = 0; i_ < 4; ++i_) { \
      acc[i_][2] = MFMA_(aF[i_], bF[2], acc[i_][2]); \
      acc[i_][3] = MFMA_(aF[i_], bF[3], acc[i_][3]); } \
    __builtin_amdgcn_s_setprio(0); \
    VMW_; \
    __builtin_amdgcn_s_barrier(); \
    __builtin_amdgcn_sched_barrier(0); \
  } while (0)

template<int RELU, int RESID>
__global__ __launch_bounds__(512, 4)
void gemm128(const ushort_t* __restrict__ A, const ushort_t* __restrict__ Bw,
             const float* __restrict__ bias,
             ushort_t* __restrict__ outb, const ushort_t* __restrict__ resid,
             int N)
{
  __shared__ __align__(16) char lds[49152];
  const int tid = threadIdx.x;
  const int lane = tid & 63, w = tid >> 6;
  const int fr = lane & 15, q = lane >> 4;
  const int wm = w >> 2, wn = w & 3;          // 2M x 4N wave grid

  // bijective XCD-aware block swizzle (T1, m204 form); nwg % 8 == 0 here
  const int nwg = gridDim.x;
  const int nbx = N >> 8;
  const int qd = nwg >> 3, r8 = nwg & 7;
  const int xcd = blockIdx.x & 7, idx = blockIdx.x >> 3;
  const int wg = (xcd < r8 ? xcd * (qd + 1) : r8 * (qd + 1) + (xcd - r8) * qd) + idx;
  const int m0 = (wg / nbx) * 128, n0 = (wg % nbx) * 256;

  const int xc = (lane & 3) ^ ((lane >> 3) & 3);
  const ushort_t* gA  = A  + (size_t)(m0 + w * 16 + (lane >> 2)) * 1024 + xc * 8;
  const ushort_t* gB0 = Bw + (size_t)(n0 + w * 32 + (lane >> 2)) * 1024 + xc * 8;
  const ushort_t* gB1 = gB0 + 16 * 1024;
  const int dA  = w * 1024;
  const int dB0 = 8192 + w * 2048;

  const int cR  = fr * 64 + ((q ^ ((fr >> 1) & 3)) << 4);
  const int rbA = wm * 4096;          // + i*1024
  const int rbB = 8192 + wn * 4096;   // + j*1024

  f32x4 acc[4][4];
  #pragma unroll
  for (int i = 0; i < 4; ++i)
    #pragma unroll
    for (int j = 0; j < 4; ++j) acc[i][j] = 0.f;
  bf16x8 aF[4], bF[4];

  STG(0); STG(1);
  VM3_;
  __builtin_amdgcn_s_barrier();
  __builtin_amdgcn_sched_barrier(0);

  #pragma unroll
  for (int t = 0; t < 30; ++t) TIL(t, STG(t + 2), VM3_);
  TIL(30, (void)0, VM0_);             // drain: tile31 data fully landed
  TIL(31, (void)0, (void)0);
  __syncthreads();                    // LDS reuse for epilogue staging

  const int erow = lane >> 2;         // 0..15
  const int ecc  = lane & 3;          // 16B chunk 0..3
  char* wb = lds + w * 4096;          // private 4KB per wave
  float bvv[2][2];
  #pragma unroll
  for (int jh = 0; jh < 2; ++jh)
    #pragma unroll
    for (int jn = 0; jn < 2; ++jn)
      bvv[jh][jn] = bias ? bias[n0 + wn * 64 + jh * 32 + jn * 16 + fr] : 0.f;

  #pragma unroll
  for (int jh = 0; jh < 2; ++jh) {    // column halves (32 cols each)
    #pragma unroll
    for (int i = 0; i < 4; ++i)
      #pragma unroll
      for (int jn = 0; jn < 2; ++jn)
        #pragma unroll
        for (int rr = 0; rr < 4; ++rr) {
          const int row = i * 16 + q * 4 + rr;      // 0..63
          float v = acc[i][jh * 2 + jn][rr] + bvv[jh][jn];
          if (RELU) v = fmaxf(v, 0.f);
          const int cp = (jn * 2 + (fr >> 3)) ^ ((row >> 2) & 3);
          *(ushort_t*)(wb + row * 64 + cp * 16 + (fr & 7) * 2) = f2bf(v);
        }
    #pragma unroll
    for (int rd = 0; rd < 4; ++rd) {
      const int row = rd * 16 + erow;
      const int sc = ecc ^ ((row >> 2) & 3);
      bf16x8 seg = *(const bf16x8*)(wb + row * 64 + sc * 16);
      const size_t gaddr = (size_t)(m0 + wm * 64 + row) * N
                         + (n0 + wn * 64 + jh * 32 + ecc * 8);
      if (RESID) {
        const bf16x8 rv = *(const bf16x8*)&resid[gaddr];
        #pragma unroll
        for (int e = 0; e < 8; ++e)
          seg[e] = (short)f2bf(bf2f((ushort_t)seg[e]) + bf2f((ushort_t)rv[e]));
      }
      *(bf16x8*)&outb[gaddr] = seg;
    }
  }
}

// ---------------------------------------------------------------------------
// Legacy 128x128 GEMM — retained ONLY for the final split-K fp32-partial GEMM.
// ---------------------------------------------------------------------------
template<int RELU, int RESID, int OBF, int OF32>
__global__ __launch_bounds__(256)
void gemm_nt(const ushort_t* __restrict__ A, const ushort_t* __restrict__ Bw,
             const float* __restrict__ bias,
             ushort_t* outb, float* outf, const ushort_t* __restrict__ resid,
             int M, int N, int K, int ksteps)
{
  __shared__ ushort_t lds[16384];
  ushort_t* lsA = lds;
  ushort_t* lsB = lds + 8192;
  const int tid = threadIdx.x, lane = tid & 63, wave = tid >> 6;
  const int fr = lane & 15, q = lane >> 4;
  const int m0 = blockIdx.y * 128, n0 = blockIdx.x * 128;
  const int wm = (wave >> 1) * 64, wn = (wave & 1) * 64;
  const int kbase = blockIdx.z * ksteps * 64;

  const ushort_t* Ab = A + (size_t)m0 * K + kbase;
  const ushort_t* Bb = Bw + (size_t)n0 * K + kbase;

  const int kg = (lane & 7) ^ (lane >> 3);
  const ushort_t* gaA = Ab + (size_t)(lane >> 3) * K + kg * 8;
  const ushort_t* gaB = Bb + (size_t)(lane >> 3) * K + kg * 8;

  f32x4 acc[4][4];
  #pragma unroll
  for (int i = 0; i < 4; i++)
    #pragma unroll
    for (int j = 0; j < 4; j++) acc[i][j] = 0.f;

  int rowA[4], rowB[4];
  #pragma unroll
  for (int t = 0; t < 4; t++) {
    rowA[t] = (wm + t * 16 + fr) * 64;
    rowB[t] = (wn + t * 16 + fr) * 64;
  }
  const int sl0 = ((0 * 4 + q) ^ (fr & 7)) * 8;
  const int sl1 = ((1 * 4 + q) ^ (fr & 7)) * 8;

  for (int ks = 0; ks < ksteps; ks++) {
    __syncthreads();
    #pragma unroll
    for (int u = 0; u < 4; u++) {
      const int i = wave * 4 + u;
      gld16(gaA + ks * 64 + (size_t)i * 8 * K, lsA + i * 512);
      gld16(gaB + ks * 64 + (size_t)i * 8 * K, lsB + i * 512);
    }
    __syncthreads();
    #pragma unroll
    for (int s = 0; s < 2; s++) {
      const int sl = s ? sl1 : sl0;
      bf16x8 af[4], bfv[4];
      #pragma unroll
      for (int t = 0; t < 4; t++) {
        af[t]  = *(const bf16x8*)(lsA + rowA[t] + sl);
        bfv[t] = *(const bf16x8*)(lsB + rowB[t] + sl);
      }
      #pragma unroll
      for (int i = 0; i < 4; i++)
        #pragma unroll
        for (int j = 0; j < 4; j++)
          acc[i][j] = MFMA_(af[i], bfv[j], acc[i][j]);
    }
  }

  if (OF32) {  // fp32 split-K partial (final GEMM only; small output)
    float* po = outf + (size_t)blockIdx.z * M * N;
    #pragma unroll
    for (int i = 0; i < 4; i++) {
      const int rb = m0 + wm + i * 16 + q * 4;
      #pragma unroll
      for (int j = 0; j < 4; j++) {
        const int col = n0 + wn + j * 16 + fr;
        #pragma unroll
        for (int rr = 0; rr < 4; rr++)
          po[(size_t)(rb + rr) * N + col] = acc[i][j][rr];
      }
    }
  }
}

// ---------------------------------------------------------------------------
// Fused attention: one block per (head, batch). qkv:[BT,3072] bf16.
// R12: swapped QK^T — sacc[jt] = mfma(K_tile, Q) = S^T. Lane (fr,q) holds
// query = itc*16+fr, keys = jt*16 + q*4 + rr. Softmax lane-local + 2 shfl.
// ---------------------------------------------------------------------------
#define KST 136   // Kls row stride (bf16): 272B rows, 2-way banks (free)
#define VST 120   // Vt row stride (bf16)
#define PST 120   // Pls row stride (bf16)

__global__ __launch_bounds__(256)
void attn_kernel(const ushort_t* __restrict__ qkv, ushort_t* __restrict__ ctx)
{
  __shared__ ushort_t Kls[112 * KST];  // 30464 B
  __shared__ ushort_t Vt[128 * VST];   // 30720 B
  __shared__ ushort_t Pls[64 * PST];   // 15360 B  (total 76544 B -> 2 blk/CU)
  const int tid = threadIdx.x, lane = tid & 63, wave = tid >> 6;
  const int fr = lane & 15, q = lane >> 4;
  const int hh = blockIdx.x, bb = blockIdx.y;
  const size_t base = (size_t)bb * T_ * DQ_;
  const ushort_t* Qb = qkv + base + hh * HD_;
  const ushort_t* Kb = qkv + base + D_ + hh * HD_;
  const ushort_t* Vb = qkv + base + 2 * D_ + hh * HD_;

  for (int e = tid; e < 1600; e += 256) {
    const int j = e >> 4, kc = e & 15;
    *(bf16x8*)&Kls[j * KST + kc * 8] = *(const bf16x8*)(Kb + (size_t)j * DQ_ + kc * 8);
  }
  for (int e = tid; e < 12 * KST; e += 256) Kls[100 * KST + e] = 0;
  for (int e = tid; e < 1600; e += 256) {
    const int j = e >> 4, dc = e & 15;
    const bf16x8 v = *(const bf16x8*)(Vb + (size_t)j * DQ_ + dc * 8);
    #pragma unroll
    for (int u = 0; u < 8; u++) Vt[(dc * 8 + u) * VST + j] = (ushort_t)v[u];
  }
  for (int e = tid; e < 128 * 12; e += 256) {
    const int d = e / 12, j = e - d * 12;
    Vt[d * VST + 100 + j] = 0;
  }
  __syncthreads();

  #pragma unroll
  for (int c = 0; c < 2; c++) {
    if (c) __syncthreads();
    const int it  = c * 4 + wave;
    const bool wlive = (it < 7);
    const int itc = wlive ? it : 6;
    const int qrow = min(itc * 16 + fr, T_ - 1);
    bf16x8 aq[4];
    #pragma unroll
    for (int ks = 0; ks < 4; ks++)
      aq[ks] = *(const bf16x8*)(Qb + (size_t)qrow * DQ_ + ks * 32 + q * 8);
    // ---- swapped QK^T: sacc[jt] = S^T tile (rows=keys, cols=queries) ----
    f32x4 sacc[7];
    #pragma unroll
    for (int jt = 0; jt < 7; jt++) sacc[jt] = 0.f;
    #pragma unroll
    for (int ks = 0; ks < 4; ks++) {
      const int kk = ks * 32 + q * 8;
      #pragma unroll
      for (int jt = 0; jt < 7; jt++) {
        const bf16x8 kb = *(const bf16x8*)&Kls[(jt * 16 + fr) * KST + kk];
        sacc[jt] = MFMA_(kb, aq[ks], sacc[jt]);     // D[key][query]
      }
    }
    // ---- lane-local softmax: this lane's query = itc*16+fr,
    //      its 28 keys = jt*16 + q*4 + rr ----
    float sv[7][4];
    float mx = -1e30f;
    #pragma unroll
    for (int jt = 0; jt < 7; jt++)
      #pragma unroll
      for (int rr = 0; rr < 4; rr++) {
        float s = sacc[jt][rr] * SCALE_;
        if (jt == 6 && (q * 4 + rr) >= 4) s = -1e30f;   // keys 100..111
        sv[jt][rr] = s;
        mx = fmaxf(mx, s);
      }
    mx = fmaxf(mx, __shfl_xor(mx, 16));
    mx = fmaxf(mx, __shfl_xor(mx, 32));
    float sum = 0.f;
    #pragma unroll
    for (int jt = 0; jt < 7; jt++)
      #pragma unroll
      for (int rr = 0; rr < 4; rr++) {
        sv[jt][rr] = __expf(sv[jt][rr] - mx);
        sum += sv[jt][rr];
      }
    sum += __shfl_xor(sum, 16);
    sum += __shfl_xor(sum, 32);
    const float inv = 1.f / sum;
    if (wlive) {
      #pragma unroll
      for (int jt = 0; jt < 7; jt++)
        #pragma unroll
        for (int rr = 0; rr < 4; rr++)
          Pls[(wave * 16 + fr) * PST + jt * 16 + q * 4 + rr] =
              f2bf(sv[jt][rr] * inv);
    }
    __syncthreads();
    const int mtc = (c == 0) ? 4 : 3;
    f32x4 cacc[4][2];
    #pragma unroll
    for (int i = 0; i < 4; i++) { cacc[i][0] = 0.f; cacc[i][1] = 0.f; }
    #pragma unroll
    for (int ks = 0; ks < 4; ks++) {
      const int kk = ks * 32 + q * 8;
      const bool live = (ks < 3) || (q < 2);
      bf16x8 v0 = 0, v1 = 0;
      if (live) {
        v0 = *(const bf16x8*)&Vt[((wave * 2 + 0) * 16 + fr) * VST + kk];
        v1 = *(const bf16x8*)&Vt[((wave * 2 + 1) * 16 + fr) * VST + kk];
      }
      #pragma unroll
      for (int mt = 0; mt < 4; mt++) {
        if (mt < mtc) {
          bf16x8 a = 0;
          if (live) a = *(const bf16x8*)&Pls[(mt * 16 + fr) * PST + kk];
          cacc[mt][0] = MFMA_(a, v0, cacc[mt][0]);
          cacc[mt][1] = MFMA_(a, v1, cacc[mt][1]);
        }
      }
    }
    #pragma unroll
    for (int mt = 0; mt < 4; mt++) {
      if (mt < mtc) {
        #pragma unroll
        for (int nn = 0; nn < 2; nn++) {
          const int col = hh * HD_ + (wave * 2 + nn) * 16 + fr;
          #pragma unroll
          for (int rr = 0; rr < 4; rr++) {
            const int r = c * 64 + mt * 16 + q * 4 + rr;
            if (r < T_)
              ctx[(size_t)(bb * T_ + r) * D_ + col] = f2bf(cacc[mt][nn][rr]);
          }
        }
      }
    }
  }
}

// ---------------------------------------------------------------------------
// LayerNorm: bf16 in -> bf16 out (fp32 stats). One block per row.
// ---------------------------------------------------------------------------
__global__ __launch_bounds__(256)
void ln_kernel(const ushort_t* __restrict__ in, ushort_t* __restrict__ outb,
               const float* __restrict__ g, const float* __restrict__ bta)
{
  const int row = blockIdx.x, tid = threadIdx.x;
  const int c4 = tid * 4;
  const ushort4 uv = *(const ushort4*)(in + (size_t)row * D_ + c4);
  const float v0 = bf2f(uv.x), v1 = bf2f(uv.y), v2 = bf2f(uv.z), v3 = bf2f(uv.w);
  float s  = v0 + v1 + v2 + v3;
  float ss = v0*v0 + v1*v1 + v2*v2 + v3*v3;
  #pragma unroll
  for (int o = 1; o < 64; o <<= 1) {
    s  += __shfl_xor(s, o);
    ss += __shfl_xor(ss, o);
  }
  __shared__ float red[8];
  const int lane = tid & 63, wave = tid >> 6;
  if (lane == 0) { red[wave] = s; red[4 + wave] = ss; }
  __syncthreads();
  s  = red[0] + red[1] + red[2] + red[3];
  ss = red[4] + red[5] + red[6] + red[7];
  const float mean = s * (1.f / D_);
  const float var  = ss * (1.f / D_) - mean * mean;
  const float rstd = rsqrtf(var + 1e-5f);
  const float4 gv = *(const float4*)(g + c4);
  const float4 bv = *(const float4*)(bta + c4);
  ushort4 ob = { f2bf((v0 - mean) * rstd * gv.x + bv.x),
                 f2bf((v1 - mean) * rstd * gv.y + bv.y),
                 f2bf((v2 - mean) * rstd * gv.z + bv.z),
                 f2bf((v3 - mean) * rstd * gv.w + bv.w) };
  *(ushort4*)(outb + (size_t)row * D_ + c4) = ob;
}

// ---------------------------------------------------------------------------
// PE table: pe[t][d] for t<T, d<D. 100 blocks x 256 thr; 512 sincos pairs/row.
// ---------------------------------------------------------------------------
__global__ __launch_bounds__(256)
void pe_init(float* __restrict__ pe)
{
  const int t = blockIdx.x;
  #pragma unroll
  for (int j = 0; j < 2; ++j) {
    const int k = threadIdx.x + j * 256;        // 0..511
    const float ang = (float)t * expf((float)k * -0.017988946039015984f);
    float s, c;
    sincosf(ang, &s, &c);
    pe[t * D_ + 2 * k]     = s;
    pe[t * D_ + 2 * k + 1] = c;
  }
}

// ---------------------------------------------------------------------------
// Embedding: h = x@Wi + bi + pe[t,:] -> bf16. One block per token row.
// ---------------------------------------------------------------------------
__global__ __launch_bounds__(256)
void embed_kernel(const float* __restrict__ x, const float* __restrict__ Wi,
                  const float* __restrict__ bi, const float* __restrict__ pe,
                  ushort_t* __restrict__ hbf)
{
  const int row = blockIdx.x;
  const int t = row % T_;
  const int c = threadIdx.x * 4;
  float xv[6];
  #pragma unroll
  for (int i = 0; i < 6; i++) xv[i] = x[row * 6 + i];
  const float4 pv = *(const float4*)(pe + t * D_ + c);
  const float4 bv = *(const float4*)(bi + c);
  float a0 = bv.x + pv.x, a1 = bv.y + pv.y, a2 = bv.z + pv.z, a3 = bv.w + pv.w;
  #pragma unroll
  for (int i = 0; i < 6; i++) {
    const float4 wv = *(const float4*)(Wi + i * D_ + c);
    a0 += xv[i] * wv.x; a1 += xv[i] * wv.y;
    a2 += xv[i] * wv.z; a3 += xv[i] * wv.w;
  }
  ushort4 ob = { f2bf(a0), f2bf(a1), f2bf(a2), f2bf(a3) };
  *(ushort4*)(hbf + (size_t)row * D_ + c) = ob;
}

// All weight tensors -> bf16 in one launch.
#define NQW (L_*DQ_*D_)   // 12582912
#define NDW (L_*D_*D_)    //  4194304
__global__ void cvt_all(const float* __restrict__ qw, const float* __restrict__ ow,
                        const float* __restrict__ f1, const float* __restrict__ f2,
                        ushort_t* wq, ushort_t* wo, ushort_t* w1, ushort_t* w2)
{
  const size_t i = ((size_t)blockIdx.x * 256 + threadIdx.x) * 4;
  const float* s; ushort_t* d; size_t off;
  if (i < NQW)                { s = qw; d = wq; off = i; }
  else if (i < NQW + NDW)     { s = ow; d = wo; off = i - NQW; }
  else if (i < NQW + 2*NDW)   { s = f1; d = w1; off = i - NQW - NDW; }
  else                        { s = f2; d = w2; off = i - NQW - 2*NDW; }
  const float4 v = *(const float4*)(s + off);
  ushort4 o = { f2bf(v.x), f2bf(v.y), f2bf(v.z), f2bf(v.w) };
  *(ushort4*)(d + off) = o;
}

// Wo [KFIN,256] fp32 -> Wot [256,KFIN] bf16
__global__ __launch_bounds__(256)
void transpose_wo(const float* __restrict__ src, ushort_t* __restrict__ dst)
{
  __shared__ float tile[64][65];
  const int k0 = blockIdx.x * 64, n0 = blockIdx.y * 64;
  const int tc = threadIdx.x & 63, tr = threadIdx.x >> 6;
  #pragma unroll
  for (int i = 0; i < 16; i++) {
    const int r = i * 4 + tr;
    tile[r][tc] = src[(size_t)(k0 + r) * OUT_ + n0 + tc];
  }
  __syncthreads();
  #pragma unroll
  for (int i = 0; i < 16; i++) {
    const int n = i * 4 + tr;
    dst[(size_t)(n0 + n) * KFIN_ + k0 + tc] = f2bf(tile[tc][n]);
  }
}

__global__ void reduce_final(const float* __restrict__ part,
                             const float* __restrict__ bo, float* __restrict__ out)
{
  const int i = blockIdx.x * 256 + threadIdx.x;   // 65536 outputs
  float s = bo[i & (OUT_ - 1)];
  for (int z = 0; z < KSPLIT_; z++) s += part[(size_t)z * OUT_ * OUT_ + i];
  out[i] = s;
}

// ---------------------------------------------------------------------------
extern "C" void kernel_launch(void* const* d_in, const int* in_sizes, int n_in,
                              void* d_out, int out_size, void* d_ws, size_t ws_size,
                              hipStream_t stream)
{
  (void)in_sizes; (void)n_in; (void)out_size; (void)ws_size;
  const float* x     = (const float*)d_in[0];
  const float* Wi    = (const float*)d_in[1];
  const float* bi    = (const float*)d_in[2];
  const float* qkv_w = (const float*)d_in[3];
  const float* qkv_b = (const float*)d_in[4];
  const float* out_w = (const float*)d_in[5];
  const float* out_b = (const float*)d_in[6];
  const float* ff1_w = (const float*)d_in[7];
  const float* ff1_b = (const float*)d_in[8];
  const float* ff2_w = (const float*)d_in[9];
  const float* ff2_b = (const float*)d_in[10];
  const float* ln1_g = (const float*)d_in[11];
  const float* ln1_b = (const float*)d_in[12];
  const float* ln2_g = (const float*)d_in[13];
  const float* ln2_b = (const float*)d_in[14];
  const float* Wo    = (const float*)d_in[15];
  const float* bo    = (const float*)d_in[16];
  float* out = (float*)d_out;

  // workspace layout — ~313 MiB peak
  char* p = (char*)d_ws;
  ushort_t* hbf  = (ushort_t*)p; p += (size_t)BT_ * D_ * 2;     //  52.4 MB
  ushort_t* qkvb = (ushort_t*)p; p += (size_t)BT_ * DQ_ * 2;    // 157.3 MB
  ushort_t* ctxb = (ushort_t*)p; p += (size_t)BT_ * D_ * 2;     //  52.4 MB
  ushort_t* wq   = (ushort_t*)p; p += (size_t)NQW * 2;          //  25.2 MB
  ushort_t* wo   = (ushort_t*)p; p += (size_t)NDW * 2;          //   8.4 MB
  ushort_t* w1   = (ushort_t*)p; p += (size_t)NDW * 2;          //   8.4 MB
  ushort_t* w2   = (ushort_t*)p; p += (size_t)NDW * 2;          //   8.4 MB
  float*    pe   = (float*)p;    p += (size_t)T_ * D_ * 4;      //   0.4 MB
  ushort_t* ffact = qkvb;                         // qkv dead after attention
  ushort_t* sum   = qkvb + (size_t)BT_ * D_;      // pre-LN sum (slot 1)
  ushort_t* wot   = ctxb;                         // ctx dead after last out-proj
  float*    part  = (float*)qkvb;                 // final split-K partials

  cvt_all<<<dim3((NQW + 3*NDW) / 1024), 256, 0, stream>>>(
      qkv_w, out_w, ff1_w, ff2_w, wq, wo, w1, w2);
  pe_init<<<dim3(T_), 256, 0, stream>>>(pe);
  embed_kernel<<<dim3(BT_), 256, 0, stream>>>(x, Wi, bi, pe, hbf);

  for (int i = 0; i < L_; i++) {
    // qkv = h @ qkv_w^T + b  -> bf16   (gemm256: measured ~160us)
    gemm256<0,0><<<dim3((BT_/256)*(DQ_/256)), 512, 0, stream>>>(
        hbf, wq + (size_t)i * DQ_ * D_, qkv_b + i * DQ_, qkvb, nullptr, DQ_);
    attn_kernel<<<dim3(H_, B_), 256, 0, stream>>>(qkvb, ctxb);
    // sum = ctx @ out_w^T + b + h   (gemm128: 800 wgs, 2 blk/CU)
    gemm128<0,1><<<dim3((BT_/128)*(D_/256)), 512, 0, stream>>>(
        ctxb, wo + (size_t)i * D_ * D_, out_b + i * D_, sum, hbf, D_);
    ln_kernel<<<dim3(BT_), 256, 0, stream>>>(sum, hbf, ln1_g + i * D_, ln1_b + i * D_);
    // ff = relu(h @ ff1^T + b) -> bf16
    gemm128<1,0><<<dim3((BT_/128)*(D_/256)), 512, 0, stream>>>(
        hbf, w1 + (size_t)i * D_ * D_, ff1_b + i * D_, ffact, nullptr, D_);
    // sum = ff @ ff2^T + b + h   (bf16)
    gemm128<0,1><<<dim3((BT_/128)*(D_/256)), 512, 0, stream>>>(
        ffact, w2 + (size_t)i * D_ * D_, ff2_b + i * D_, sum, hbf, D_);
    ln_kernel<<<dim3(BT_), 256, 0, stream>>>(sum, hbf, ln2_g + i * D_, ln2_b + i * D_);
  }

  // final: out = h.reshape(256,102400) @ Wo + bo   (split-K partials + reduce)
  transpose_wo<<<dim3(KFIN_/64, OUT_/64), 256, 0, stream>>>(Wo, wot);
  gemm_nt<0,0,0,1><<<dim3(OUT_/128, OUT_/128, KSPLIT_), 256, 0, stream>>>(
      hbf, wot, nullptr, nullptr, part, nullptr,
      OUT_, OUT_, KFIN_, KFIN_ / (KSPLIT_ * 64));
  reduce_final<<<dim3(OUT_ * OUT_ / 256), 256, 0, stream>>>(part, bo, out);
}